// Round 1
// baseline (2548.173 us; speedup 1.0000x reference)
//
#include <hip/hip_runtime.h>
#include <cstdint>
#include <cmath>

#define N0   6144
#define FD   320
#define NN1  4915
#define NN2  2949
#define CAP  384
#define SORTN 8192

// ---------------- adjacency build: dense row -> compact column list ----------------
__global__ __launch_bounds__(256) void build_adj_k(const float* __restrict__ A,
                                                   int* __restrict__ adj, int* __restrict__ deg) {
  int w = blockIdx.x * 4 + (threadIdx.x >> 6);
  int lane = threadIdx.x & 63;
  if (w >= N0) return;
  const float* row = A + (size_t)w * N0;
  int* dst = adj + (size_t)w * CAP;
  int base = 0;
  for (int j0 = 0; j0 < N0; j0 += 64) {
    float v = row[j0 + lane];
    unsigned long long m = __ballot(v > 0.0f);
    if (v > 0.0f) dst[base + __popcll(m & ((1ull << lane) - 1ull))] = j0 + lane;
    base += (int)__popcll(m);
  }
  if (lane == 0) deg[w] = base;
}

// subgraph adjacency: new row r <- old row idx[r], keep cols with inv[c]>=0, renumber
__global__ __launch_bounds__(256) void sub_adj_k(const int* __restrict__ adjs, const int* __restrict__ degs,
                                                 const int* __restrict__ idx, const int* __restrict__ inv,
                                                 int* __restrict__ adjd, int* __restrict__ degd, int k) {
  int w = blockIdx.x * 4 + (threadIdx.x >> 6);
  int lane = threadIdx.x & 63;
  if (w >= k) return;
  int o = idx[w];
  int d = degs[o];
  const int* src = adjs + (size_t)o * CAP;
  int* dst = adjd + (size_t)w * CAP;
  int base = 0;
  for (int t0 = 0; t0 < d; t0 += 64) {
    int tt = t0 + lane;
    int p = -1;
    if (tt < d) p = inv[src[tt]];
    unsigned long long m = __ballot(p >= 0);
    if (p >= 0) dst[base + __popcll(m & ((1ull << lane) - 1ull))] = p;
    base += (int)__popcll(m);
  }
  if (lane == 0) degd[w] = base;
}

// ---------------- sparse neighbor sum: Y[r,:] = sum_{j in N(r)} X[j,:] ----------------
__global__ __launch_bounds__(256) void spmm_k(const int* __restrict__ adj, const int* __restrict__ deg,
                                              const float* __restrict__ X, float* __restrict__ Y, int n) {
  int w = blockIdx.x * 4 + (threadIdx.x >> 6);
  int lane = threadIdx.x & 63;
  if (w >= n) return;
  int d = deg[w];
  const int* row = adj + (size_t)w * CAP;
  float a0=0.f,a1=0.f,a2=0.f,a3=0.f,a4=0.f;
  for (int t = 0; t < d; ++t) {
    const float* xr = X + (size_t)row[t] * FD + lane;
    a0 += xr[0]; a1 += xr[64]; a2 += xr[128]; a3 += xr[192]; a4 += xr[256];
  }
  float* yr = Y + (size_t)w * FD + lane;
  yr[0]=a0; yr[64]=a1; yr[128]=a2; yr[192]=a3; yr[256]=a4;
}

// masked variant (fused unpool + A@Xn): source row = inv[col] into pooled X, skip if -1
__global__ __launch_bounds__(256) void mspmm_k(const int* __restrict__ adj, const int* __restrict__ deg,
                                               const int* __restrict__ inv,
                                               const float* __restrict__ Xp, float* __restrict__ Y, int n) {
  int w = blockIdx.x * 4 + (threadIdx.x >> 6);
  int lane = threadIdx.x & 63;
  if (w >= n) return;
  int d = deg[w];
  const int* row = adj + (size_t)w * CAP;
  float a0=0.f,a1=0.f,a2=0.f,a3=0.f,a4=0.f;
  for (int t = 0; t < d; ++t) {
    int p = inv[row[t]];
    if (p >= 0) {
      const float* xr = Xp + (size_t)p * FD + lane;
      a0 += xr[0]; a1 += xr[64]; a2 += xr[128]; a3 += xr[192]; a4 += xr[256];
    }
  }
  float* yr = Y + (size_t)w * FD + lane;
  yr[0]=a0; yr[64]=a1; yr[128]=a2; yr[192]=a3; yr[256]=a4;
}

// ---------------- fp32 tiled GEMM: C[n x 320] = A[n x K] @ W[K x 320] (+bias)(+add) ----------------
#define BM 64
#define BN 64
#define BK 16
__global__ __launch_bounds__(256) void gemm_k(const float* __restrict__ A, const float* __restrict__ W,
                                              const float* __restrict__ bias, const float* __restrict__ add,
                                              float* __restrict__ C, int n, int K) {
  __shared__ float As[BK][BM + 4];
  __shared__ float Bs[BK][BN + 4];
  int t = threadIdx.x;
  int tx = t & 15, ty = t >> 4;
  int row0 = blockIdx.x * BM, col0 = blockIdx.y * BN;
  float acc[4][4] = {};
  int ar = t >> 2;
  int ak = (t & 3) << 2;
  int bk = t >> 4;
  int bc = (t & 15) << 2;
  for (int k0 = 0; k0 < K; k0 += BK) {
    float4 av = make_float4(0.f, 0.f, 0.f, 0.f);
    int grow = row0 + ar;
    if (grow < n) av = *(const float4*)(A + (size_t)grow * K + k0 + ak);
    As[ak + 0][ar] = av.x; As[ak + 1][ar] = av.y; As[ak + 2][ar] = av.z; As[ak + 3][ar] = av.w;
    float4 bv = *(const float4*)(W + (size_t)(k0 + bk) * FD + col0 + bc);
    *(float4*)&Bs[bk][bc] = bv;
    __syncthreads();
#pragma unroll
    for (int kk = 0; kk < BK; ++kk) {
      float af[4], bf[4];
      *(float4*)af = *(const float4*)&As[kk][ty * 4];
      *(float4*)bf = *(const float4*)&Bs[kk][tx * 4];
#pragma unroll
      for (int i = 0; i < 4; ++i)
#pragma unroll
        for (int j = 0; j < 4; ++j) acc[i][j] += af[i] * bf[j];
    }
    __syncthreads();
  }
#pragma unroll
  for (int i = 0; i < 4; ++i) {
    int r = row0 + ty * 4 + i;
    if (r >= n) continue;
    int c = col0 + tx * 4;
    float4 v;
    v.x = acc[i][0]; v.y = acc[i][1]; v.z = acc[i][2]; v.w = acc[i][3];
    if (bias) { v.x += bias[c]; v.y += bias[c+1]; v.z += bias[c+2]; v.w += bias[c+3]; }
    if (add) {
      const float* ad = add + (size_t)r * FD + c;
      v.x += ad[0]; v.y += ad[1]; v.z += ad[2]; v.w += ad[3];
    }
    *(float4*)(C + (size_t)r * FD + c) = v;
  }
}

// ---------------- GAT helpers ----------------
__global__ __launch_bounds__(256) void esed_k(const float* __restrict__ h, const float* __restrict__ a,
                                              float* __restrict__ es, float* __restrict__ ed, int n) {
  int w = blockIdx.x * 4 + (threadIdx.x >> 6);
  int lane = threadIdx.x & 63;
  if (w >= n) return;
  const float* hr = h + (size_t)w * FD;
  const float* a2 = a + FD;
  float sa = 0.f, sb = 0.f;
#pragma unroll
  for (int c = 0; c < 5; ++c) {
    float hv = hr[lane + 64 * c];
    sa += hv * a[lane + 64 * c];
    sb += hv * a2[lane + 64 * c];
  }
  for (int o = 32; o; o >>= 1) { sa += __shfl_xor(sa, o); sb += __shfl_xor(sb, o); }
  if (lane == 0) { es[w] = sa; ed[w] = sb; }
}

// fused masked-softmax GAT row: out = elu( softmax_edges(LR(es_i+ed_j)) @ h )
__global__ __launch_bounds__(256) void gat_k(const int* __restrict__ adj, const int* __restrict__ deg,
                                             const float* __restrict__ h, const float* __restrict__ es,
                                             const float* __restrict__ ed, float* __restrict__ out, int n) {
  int w = blockIdx.x * 4 + (threadIdx.x >> 6);
  int lane = threadIdx.x & 63;
  if (w >= n) return;
  int d = deg[w];
  const int* row = adj + (size_t)w * CAP;
  float esr = es[w];
  float m = -INFINITY;
  for (int t = lane; t < d; t += 64) m = fmaxf(m, ed[row[t]]);
  for (int o = 32; o; o >>= 1) m = fmaxf(m, __shfl_xor(m, o));
  float emax = esr + m;
  emax = emax >= 0.f ? emax : 0.2f * emax;   // LR monotone: max of LR = LR of max
  float Z = 0.f, a0=0.f,a1=0.f,a2=0.f,a3=0.f,a4=0.f;
  for (int t = 0; t < d; ++t) {
    int j = row[t];
    float e = esr + ed[j];
    e = e >= 0.f ? e : 0.2f * e;
    float wgt = expf(e - emax);
    Z += wgt;
    const float* xr = h + (size_t)j * FD + lane;
    a0 += wgt * xr[0]; a1 += wgt * xr[64]; a2 += wgt * xr[128]; a3 += wgt * xr[192]; a4 += wgt * xr[256];
  }
  float* yr = out + (size_t)w * FD + lane;
  float v;
  v = a0 / Z; yr[0]   = v > 0.f ? v : expm1f(v);
  v = a1 / Z; yr[64]  = v > 0.f ? v : expm1f(v);
  v = a2 / Z; yr[128] = v > 0.f ? v : expm1f(v);
  v = a3 / Z; yr[192] = v > 0.f ? v : expm1f(v);
  v = a4 / Z; yr[256] = v > 0.f ? v : expm1f(v);
}

// ---------------- pooling ----------------
__global__ __launch_bounds__(256) void score_k(const float* __restrict__ X, const float* __restrict__ pw,
                                               const float* __restrict__ pb, float* __restrict__ sc, int n) {
  int w = blockIdx.x * 4 + (threadIdx.x >> 6);
  int lane = threadIdx.x & 63;
  if (w >= n) return;
  const float* xr = X + (size_t)w * FD;
  float s = 0.f;
#pragma unroll
  for (int c = 0; c < 5; ++c) s += xr[lane + 64 * c] * pw[lane + 64 * c];
  for (int o = 32; o; o >>= 1) s += __shfl_xor(s, o);
  if (lane == 0) {
    float u = (s + pb[0]) / 100.0f;
    sc[w] = 1.0f / (1.0f + expf(-u));
  }
}

// single-block bitonic sort, descending by (score_bits, ~index) packed u64.
// scores are sigmoid outputs in (0,1): positive floats are monotone as uint32.
__global__ __launch_bounds__(1024) void topk_sort_k(const float* __restrict__ scores, int n,
                                                    int* __restrict__ idx_out, float* __restrict__ vals_out, int k) {
  __shared__ unsigned long long s[SORTN];
  int t = threadIdx.x;
  for (int i = t; i < SORTN; i += 1024) {
    unsigned long long key = 0ull;
    if (i < n) {
      unsigned int sb = __float_as_uint(scores[i]);
      key = ((unsigned long long)sb << 32) | (unsigned int)(~i);
    }
    s[i] = key;
  }
  __syncthreads();
  for (int kk = 2; kk <= SORTN; kk <<= 1) {
    for (int j = kk >> 1; j > 0; j >>= 1) {
      for (int i = t; i < SORTN; i += 1024) {
        int p = i ^ j;
        if (p > i) {
          unsigned long long a = s[i], b = s[p];
          bool descend = ((i & kk) == 0);
          bool sw = descend ? (a < b) : (a > b);
          if (sw) { s[i] = b; s[p] = a; }
        }
      }
      __syncthreads();
    }
  }
  for (int i = t; i < k; i += 1024) {
    unsigned long long key = s[i];
    idx_out[i] = (int)(~((unsigned int)key));
    vals_out[i] = __uint_as_float((unsigned int)(key >> 32));
  }
}

__global__ void fill_i32_k(int* __restrict__ p, int v, int n) {
  int i = blockIdx.x * 256 + threadIdx.x;
  if (i < n) p[i] = v;
}
__global__ void scatter_inv_k(const int* __restrict__ idx, int* __restrict__ inv, int k) {
  int i = blockIdx.x * 256 + threadIdx.x;
  if (i < k) inv[idx[i]] = i;
}
__global__ void gather_scale_k(const float* __restrict__ X, const int* __restrict__ idx,
                               const float* __restrict__ vals, float* __restrict__ out, int k) {
  int i = blockIdx.x * 256 + threadIdx.x;
  if (i >= k * FD) return;
  int r = i / FD, c = i - r * FD;
  out[i] = X[(size_t)idx[r] * FD + c] * vals[r];
}
__global__ void concat_k(const float* __restrict__ Xa, const float* __restrict__ Xb,
                         float* __restrict__ out, int n) {
  int i = blockIdx.x * 256 + threadIdx.x;
  if (i >= n * 2 * FD) return;
  int r = i / (2 * FD), c = i - r * 2 * FD;
  out[i] = (c < FD) ? Xa[(size_t)r * FD + c] : Xb[(size_t)r * FD + (c - FD)];
}

// ---------------- host ----------------
static inline dim3 wgrid(int n) { return dim3((unsigned)((n + 3) / 4)); }
static inline unsigned cdiv(int a, int b) { return (unsigned)((a + b - 1) / b); }

extern "C" void kernel_launch(void* const* d_in, const int* in_sizes, int n_in,
                              void* d_out, int out_size, void* d_ws, size_t ws_size,
                              hipStream_t stream) {
  const float* A      = (const float*)d_in[0];
  const float* X0     = (const float*)d_in[1];
  const float* sg_W   = (const float*)d_in[2];
  const float* sg_a   = (const float*)d_in[3];
  const float* bg_W   = (const float*)d_in[4];
  const float* bg_a   = (const float*)d_in[5];
  const float* eg_W   = (const float*)d_in[6];
  const float* eg_a   = (const float*)d_in[7];
  const float* down_W = (const float*)d_in[8];
  const float* down_b = (const float*)d_in[9];
  const float* up_W   = (const float*)d_in[10];
  const float* up_b   = (const float*)d_in[11];
  const float* pool_w = (const float*)d_in[12];
  const float* pool_b = (const float*)d_in[13];
  float* out = (float*)d_out;
  char* ws = (char*)d_ws;

  size_t off = 0;
  auto alloc = [&](size_t bytes) -> char* {
    char* p = ws + off;
    off += (bytes + 255) & ~(size_t)255;
    return p;
  };
  int* adj0  = (int*)alloc((size_t)N0 * CAP * 4);
  int* deg0  = (int*)alloc((size_t)N0 * 4);
  int* adj1a = (int*)alloc((size_t)NN1 * CAP * 4);
  int* deg1a = (int*)alloc((size_t)NN1 * 4);
  int* adj1b = (int*)alloc((size_t)NN1 * CAP * 4);
  int* deg1b = (int*)alloc((size_t)NN1 * 4);
  int* adj2  = (int*)alloc((size_t)NN2 * CAP * 4);
  int* deg2  = (int*)alloc((size_t)NN2 * 4);
  int* inv0a = (int*)alloc((size_t)N0 * 4);
  int* inv0b = (int*)alloc((size_t)N0 * 4);
  int* inv1a = (int*)alloc((size_t)NN1 * 4);
  int* inv1b = (int*)alloc((size_t)NN1 * 4);
  int* idx0a = (int*)alloc((size_t)NN1 * 4);
  int* idx0b = (int*)alloc((size_t)NN1 * 4);
  int* idx1a = (int*)alloc((size_t)NN2 * 4);
  int* idx1b = (int*)alloc((size_t)NN2 * 4);
  float* scores = (float*)alloc((size_t)N0 * 4);
  float* vals   = (float*)alloc((size_t)N0 * 4);
  float* es     = (float*)alloc((size_t)N0 * 4);
  float* ed     = (float*)alloc((size_t)N0 * 4);
  float* hbuf   = (float*)alloc((size_t)N0 * FD * 4);
  float* S      = (float*)alloc((size_t)N0 * FD * 4);
  float* Xcur   = (float*)alloc((size_t)N0 * FD * 4);
  float* d0a    = (float*)alloc((size_t)N0 * FD * 4);
  float* d1a    = (float*)alloc((size_t)NN1 * FD * 4);
  float* d0b    = (float*)alloc((size_t)N0 * FD * 4);
  float* d1b    = (float*)alloc((size_t)NN1 * FD * 4);
  float* Xp1    = (float*)alloc((size_t)NN1 * FD * 4);
  float* Xp2    = (float*)alloc((size_t)NN2 * FD * 4);
  float* Xb     = (float*)alloc((size_t)NN2 * FD * 4);
  float* Xu1    = (float*)alloc((size_t)NN1 * FD * 4);
  float* Xu0    = (float*)alloc((size_t)N0 * FD * 4);
  float* Xc     = (float*)alloc((size_t)N0 * 2 * FD * 4);

  dim3 b256(256), b1024(1024);

  build_adj_k<<<wgrid(N0), b256, 0, stream>>>(A, adj0, deg0);

  // sg GAT -> start (second half of d_out), also serves as org_X
  float* orgX = out + (size_t)N0 * FD;
  gemm_k<<<dim3(cdiv(N0,64),5), b256, 0, stream>>>(X0, sg_W, nullptr, nullptr, hbuf, N0, FD);
  esed_k<<<wgrid(N0), b256, 0, stream>>>(hbuf, sg_a, es, ed, N0);
  gat_k<<<wgrid(N0), b256, 0, stream>>>(adj0, deg0, hbuf, es, ed, orgX, N0);

  const float* Xin = orgX;
  for (int pass = 0; pass < 2; ++pass) {
    int* idx0p = pass ? idx0b : idx0a;
    int* inv0p = pass ? inv0b : inv0a;
    int* idx1p = pass ? idx1b : idx1a;
    int* inv1p = pass ? inv1b : inv1a;
    int* adj1p = pass ? adj1b : adj1a;
    int* deg1p = pass ? deg1b : deg1a;
    float* d0p = pass ? d0b : d0a;
    float* d1p = pass ? d1b : d1a;

    // ---- down level 0 (n = N0) ----
    spmm_k<<<wgrid(N0), b256, 0, stream>>>(adj0, deg0, Xin, S, N0);
    gemm_k<<<dim3(cdiv(N0,64),5), b256, 0, stream>>>(S, down_W, down_b, nullptr, d0p, N0, FD);
    score_k<<<wgrid(N0), b256, 0, stream>>>(d0p, pool_w, pool_b, scores, N0);
    topk_sort_k<<<dim3(1), b1024, 0, stream>>>(scores, N0, idx0p, vals, NN1);
    fill_i32_k<<<cdiv(N0,256), b256, 0, stream>>>(inv0p, -1, N0);
    scatter_inv_k<<<cdiv(NN1,256), b256, 0, stream>>>(idx0p, inv0p, NN1);
    gather_scale_k<<<cdiv(NN1*FD,256), b256, 0, stream>>>(d0p, idx0p, vals, Xp1, NN1);
    sub_adj_k<<<wgrid(NN1), b256, 0, stream>>>(adj0, deg0, idx0p, inv0p, adj1p, deg1p, NN1);

    // ---- down level 1 (n = NN1) ----
    spmm_k<<<wgrid(NN1), b256, 0, stream>>>(adj1p, deg1p, Xp1, S, NN1);
    gemm_k<<<dim3(cdiv(NN1,64),5), b256, 0, stream>>>(S, down_W + FD*FD, down_b + FD, nullptr, d1p, NN1, FD);
    score_k<<<wgrid(NN1), b256, 0, stream>>>(d1p, pool_w + FD, pool_b + 1, scores, NN1);
    topk_sort_k<<<dim3(1), b1024, 0, stream>>>(scores, NN1, idx1p, vals, NN2);
    fill_i32_k<<<cdiv(NN1,256), b256, 0, stream>>>(inv1p, -1, NN1);
    scatter_inv_k<<<cdiv(NN2,256), b256, 0, stream>>>(idx1p, inv1p, NN2);
    gather_scale_k<<<cdiv(NN2*FD,256), b256, 0, stream>>>(d1p, idx1p, vals, Xp2, NN2);
    sub_adj_k<<<wgrid(NN2), b256, 0, stream>>>(adj1p, deg1p, idx1p, inv1p, adj2, deg2, NN2);

    // ---- bottom GAT (n = NN2) ----
    gemm_k<<<dim3(cdiv(NN2,64),5), b256, 0, stream>>>(Xp2, bg_W, nullptr, nullptr, hbuf, NN2, FD);
    esed_k<<<wgrid(NN2), b256, 0, stream>>>(hbuf, bg_a, es, ed, NN2);
    gat_k<<<wgrid(NN2), b256, 0, stream>>>(adj2, deg2, hbuf, es, ed, Xb, NN2);

    // ---- up path: ALWAYS pass-1 ("a") graph state, per reference indexing ----
    mspmm_k<<<wgrid(NN1), b256, 0, stream>>>(adj1a, deg1a, inv1a, Xb, S, NN1);
    gemm_k<<<dim3(cdiv(NN1,64),5), b256, 0, stream>>>(S, up_W, up_b, d1a, Xu1, NN1, FD);
    mspmm_k<<<wgrid(N0), b256, 0, stream>>>(adj0, deg0, inv0a, Xu1, S, N0);
    gemm_k<<<dim3(cdiv(N0,64),5), b256, 0, stream>>>(S, up_W + FD*FD, up_b + FD, d0a, Xu0, N0, FD);

    // ---- end GAT on concat([Xu0, org_X]) (n = N0, K = 640) ----
    concat_k<<<cdiv(N0*2*FD,256), b256, 0, stream>>>(Xu0, orgX, Xc, N0);
    gemm_k<<<dim3(cdiv(N0,64),5), b256, 0, stream>>>(Xc, eg_W, nullptr, nullptr, hbuf, N0, 2*FD);
    esed_k<<<wgrid(N0), b256, 0, stream>>>(hbuf, eg_a, es, ed, N0);
    float* egout = pass ? out : Xcur;
    gat_k<<<wgrid(N0), b256, 0, stream>>>(adj0, deg0, hbuf, es, ed, egout, N0);
    Xin = egout;
  }
}

// Round 2
// 2102.038 us; speedup vs baseline: 1.2122x; 1.2122x over previous
//
#include <hip/hip_runtime.h>
#include <cstdint>
#include <cmath>

#define N0   6144
#define FD   320
#define NN1  4915
#define NN2  2949
#define CAP  384
#define SORTN 8192

// ---------------- adjacency build: dense row -> compact column list ----------------
__global__ __launch_bounds__(256) void build_adj_k(const float* __restrict__ A,
                                                   int* __restrict__ adj, int* __restrict__ deg) {
  int w = blockIdx.x * 4 + (threadIdx.x >> 6);
  int lane = threadIdx.x & 63;
  if (w >= N0) return;
  const float* row = A + (size_t)w * N0;
  int* dst = adj + (size_t)w * CAP;
  int base = 0;
  for (int j0 = 0; j0 < N0; j0 += 64) {
    float v = row[j0 + lane];
    unsigned long long m = __ballot(v > 0.0f);
    if (v > 0.0f) dst[base + __popcll(m & ((1ull << lane) - 1ull))] = j0 + lane;
    base += (int)__popcll(m);
  }
  if (lane == 0) deg[w] = base;
}

// subgraph adjacency: new row r <- old row idx[r], keep cols with inv[c]>=0, renumber
__global__ __launch_bounds__(256) void sub_adj_k(const int* __restrict__ adjs, const int* __restrict__ degs,
                                                 const int* __restrict__ idx, const int* __restrict__ inv,
                                                 int* __restrict__ adjd, int* __restrict__ degd, int k) {
  int w = blockIdx.x * 4 + (threadIdx.x >> 6);
  int lane = threadIdx.x & 63;
  if (w >= k) return;
  int o = idx[w];
  int d = degs[o];
  const int* src = adjs + (size_t)o * CAP;
  int* dst = adjd + (size_t)w * CAP;
  int base = 0;
  for (int t0 = 0; t0 < d; t0 += 64) {
    int tt = t0 + lane;
    int p = -1;
    if (tt < d) p = inv[src[tt]];
    unsigned long long m = __ballot(p >= 0);
    if (p >= 0) dst[base + __popcll(m & ((1ull << lane) - 1ull))] = p;
    base += (int)__popcll(m);
  }
  if (lane == 0) degd[w] = base;
}

// ================= tiled gather family =================
// One wave per row. Stage (index, weight) per 64-neighbor tile into LDS, then
// process 4 neighbors/iter: lane = (group g = lane>>4) x (sub = lane&15);
// group g handles neighbor t+g, sub covers cols sub*4 + 64*c (c=0..4) as float4.
// Cross-group shfl_xor reduce at the end.

#define GATHER_CORE(XSRC)                                                        \
  int sub = lane & 15, g = lane >> 4;                                            \
  float4 a0 = {0,0,0,0}, a1 = {0,0,0,0}, a2 = {0,0,0,0}, a3 = {0,0,0,0}, a4 = {0,0,0,0}; \
  _Pragma("unroll 2")                                                            \
  for (int t = 0; t < d; t += 4) {                                               \
    int jj = lj[t + g];                                                          \
    float ww = lw[t + g];                                                        \
    const float* base = XSRC + (size_t)jj * FD + (sub << 2);                     \
    float4 v0 = *(const float4*)(base);                                          \
    float4 v1 = *(const float4*)(base + 64);                                     \
    float4 v2 = *(const float4*)(base + 128);                                    \
    float4 v3 = *(const float4*)(base + 192);                                    \
    float4 v4 = *(const float4*)(base + 256);                                    \
    a0.x = fmaf(ww, v0.x, a0.x); a0.y = fmaf(ww, v0.y, a0.y);                    \
    a0.z = fmaf(ww, v0.z, a0.z); a0.w = fmaf(ww, v0.w, a0.w);                    \
    a1.x = fmaf(ww, v1.x, a1.x); a1.y = fmaf(ww, v1.y, a1.y);                    \
    a1.z = fmaf(ww, v1.z, a1.z); a1.w = fmaf(ww, v1.w, a1.w);                    \
    a2.x = fmaf(ww, v2.x, a2.x); a2.y = fmaf(ww, v2.y, a2.y);                    \
    a2.z = fmaf(ww, v2.z, a2.z); a2.w = fmaf(ww, v2.w, a2.w);                    \
    a3.x = fmaf(ww, v3.x, a3.x); a3.y = fmaf(ww, v3.y, a3.y);                    \
    a3.z = fmaf(ww, v3.z, a3.z); a3.w = fmaf(ww, v3.w, a3.w);                    \
    a4.x = fmaf(ww, v4.x, a4.x); a4.y = fmaf(ww, v4.y, a4.y);                    \
    a4.z = fmaf(ww, v4.z, a4.z); a4.w = fmaf(ww, v4.w, a4.w);                    \
  }                                                                              \
  /* reduce across the 4 groups (lanes l, l^16, l^32, l^48 hold same cols) */    \
  _Pragma("unroll")                                                              \
  for (int off = 16; off <= 32; off <<= 1) {                                     \
    a0.x += __shfl_xor(a0.x, off); a0.y += __shfl_xor(a0.y, off);                \
    a0.z += __shfl_xor(a0.z, off); a0.w += __shfl_xor(a0.w, off);                \
    a1.x += __shfl_xor(a1.x, off); a1.y += __shfl_xor(a1.y, off);                \
    a1.z += __shfl_xor(a1.z, off); a1.w += __shfl_xor(a1.w, off);                \
    a2.x += __shfl_xor(a2.x, off); a2.y += __shfl_xor(a2.y, off);                \
    a2.z += __shfl_xor(a2.z, off); a2.w += __shfl_xor(a2.w, off);                \
    a3.x += __shfl_xor(a3.x, off); a3.y += __shfl_xor(a3.y, off);                \
    a3.z += __shfl_xor(a3.z, off); a3.w += __shfl_xor(a3.w, off);                \
    a4.x += __shfl_xor(a4.x, off); a4.y += __shfl_xor(a4.y, off);                \
    a4.z += __shfl_xor(a4.z, off); a4.w += __shfl_xor(a4.w, off);                \
  }                                                                              \
  float4 osel = (g == 0) ? a0 : (g == 1) ? a1 : (g == 2) ? a2 : a3;

// Y[r,:] = sum_{j in N(r)} X[j,:]
__global__ __launch_bounds__(256) void spmm_k(const int* __restrict__ adj, const int* __restrict__ deg,
                                              const float* __restrict__ X, float* __restrict__ Y, int n) {
  __shared__ int ljs[4][CAP];
  __shared__ float lws[4][CAP];
  int wv = threadIdx.x >> 6, lane = threadIdx.x & 63;
  int w = blockIdx.x * 4 + wv;
  if (w >= n) return;
  int* lj = ljs[wv]; float* lw = lws[wv];
  int d = deg[w];
  const int* row = adj + (size_t)w * CAP;
  for (int t0 = 0; t0 < d; t0 += 64) {
    int tt = t0 + lane;
    lj[tt] = (tt < d) ? row[tt] : 0;
    lw[tt] = (tt < d) ? 1.0f : 0.0f;
  }
  GATHER_CORE(X)
  float* yr = Y + (size_t)w * FD;
  *(float4*)(yr + g * 64 + (sub << 2)) = osel;
  if (g == 0) *(float4*)(yr + 256 + (sub << 2)) = a4;
}

// fused unpool + A@Xn: source row = inv[col] into pooled X, skip if -1
__global__ __launch_bounds__(256) void mspmm_k(const int* __restrict__ adj, const int* __restrict__ deg,
                                               const int* __restrict__ inv,
                                               const float* __restrict__ Xp, float* __restrict__ Y, int n) {
  __shared__ int ljs[4][CAP];
  __shared__ float lws[4][CAP];
  int wv = threadIdx.x >> 6, lane = threadIdx.x & 63;
  int w = blockIdx.x * 4 + wv;
  if (w >= n) return;
  int* lj = ljs[wv]; float* lw = lws[wv];
  int d = deg[w];
  const int* row = adj + (size_t)w * CAP;
  for (int t0 = 0; t0 < d; t0 += 64) {
    int tt = t0 + lane;
    int p = -1;
    if (tt < d) p = inv[row[tt]];
    lj[tt] = p >= 0 ? p : 0;
    lw[tt] = p >= 0 ? 1.0f : 0.0f;
  }
  GATHER_CORE(Xp)
  float* yr = Y + (size_t)w * FD;
  *(float4*)(yr + g * 64 + (sub << 2)) = osel;
  if (g == 0) *(float4*)(yr + 256 + (sub << 2)) = a4;
}

// fused masked-softmax GAT row: out = elu( softmax_edges(LR(es_i+ed_j)) @ h )
__global__ __launch_bounds__(256) void gat_k(const int* __restrict__ adj, const int* __restrict__ deg,
                                             const float* __restrict__ h, const float* __restrict__ es,
                                             const float* __restrict__ ed, float* __restrict__ out, int n) {
  __shared__ int ljs[4][CAP];
  __shared__ float lws[4][CAP];
  int wv = threadIdx.x >> 6, lane = threadIdx.x & 63;
  int w = blockIdx.x * 4 + wv;
  if (w >= n) return;
  int* lj = ljs[wv]; float* lw = lws[wv];
  int d = deg[w];
  const int* row = adj + (size_t)w * CAP;
  float esr = es[w];
  // pass 1: stage indices + post-LeakyReLU logits, row max
  float m = -INFINITY;
  for (int t0 = 0; t0 < d; t0 += 64) {
    int tt = t0 + lane;
    int j = (tt < d) ? row[tt] : 0;
    float e = -INFINITY;
    if (tt < d) {
      e = esr + ed[j];
      e = e >= 0.f ? e : 0.2f * e;
    }
    lj[tt] = j;
    lw[tt] = e;
    m = fmaxf(m, e);
  }
  #pragma unroll
  for (int off = 32; off; off >>= 1) m = fmaxf(m, __shfl_xor(m, off));
  // pass 1b: exponentiate in place, accumulate Z
  float zacc = 0.f;
  for (int t0 = 0; t0 < d; t0 += 64) {
    int tt = t0 + lane;
    float wgt = expf(lw[tt] - m);   // padding e=-INF -> 0
    lw[tt] = wgt;
    zacc += wgt;
  }
  #pragma unroll
  for (int off = 32; off; off >>= 1) zacc += __shfl_xor(zacc, off);
  GATHER_CORE(h)
  float* yr = out + (size_t)w * FD;
  float4 o;
  o.x = osel.x / zacc; o.y = osel.y / zacc; o.z = osel.z / zacc; o.w = osel.w / zacc;
  o.x = o.x > 0.f ? o.x : expm1f(o.x);
  o.y = o.y > 0.f ? o.y : expm1f(o.y);
  o.z = o.z > 0.f ? o.z : expm1f(o.z);
  o.w = o.w > 0.f ? o.w : expm1f(o.w);
  *(float4*)(yr + g * 64 + (sub << 2)) = o;
  if (g == 0) {
    float4 o4;
    o4.x = a4.x / zacc; o4.y = a4.y / zacc; o4.z = a4.z / zacc; o4.w = a4.w / zacc;
    o4.x = o4.x > 0.f ? o4.x : expm1f(o4.x);
    o4.y = o4.y > 0.f ? o4.y : expm1f(o4.y);
    o4.z = o4.z > 0.f ? o4.z : expm1f(o4.z);
    o4.w = o4.w > 0.f ? o4.w : expm1f(o4.w);
    *(float4*)(yr + 256 + (sub << 2)) = o4;
  }
}

// ---------------- fp32 tiled GEMM: C[n x 320] = A[n x K] @ W[K x 320] (+bias)(+add) ----------------
template<int BM, int ROWS>
__global__ __launch_bounds__(256) void gemm_t(const float* __restrict__ A, const float* __restrict__ W,
                                              const float* __restrict__ bias, const float* __restrict__ add,
                                              float* __restrict__ C, int n, int K) {
  __shared__ float As[16][BM + 4];
  __shared__ float Bs[16][68];
  int t = threadIdx.x;
  int tx = t & 15, ty = t >> 4;
  int row0 = blockIdx.x * BM, col0 = blockIdx.y * 64;
  float acc[ROWS][4] = {};
  int ar = t >> 2;
  int ak = (t & 3) << 2;
  int bk = t >> 4;
  int bc = (t & 15) << 2;
  for (int k0 = 0; k0 < K; k0 += 16) {
#pragma unroll
    for (int rr = 0; rr < BM; rr += 64) {
      int r = ar + rr;
      float4 av = make_float4(0.f, 0.f, 0.f, 0.f);
      int grow = row0 + r;
      if (grow < n) av = *(const float4*)(A + (size_t)grow * K + k0 + ak);
      As[ak + 0][r] = av.x; As[ak + 1][r] = av.y; As[ak + 2][r] = av.z; As[ak + 3][r] = av.w;
    }
    float4 bv = *(const float4*)(W + (size_t)(k0 + bk) * FD + col0 + bc);
    *(float4*)&Bs[bk][bc] = bv;
    __syncthreads();
#pragma unroll
    for (int kk = 0; kk < 16; ++kk) {
      float bf[4];
      *(float4*)bf = *(const float4*)&Bs[kk][tx << 2];
      float af[ROWS];
#pragma unroll
      for (int i = 0; i < ROWS; i += 4) *(float4*)(af + i) = *(const float4*)&As[kk][ty * ROWS + i];
#pragma unroll
      for (int i = 0; i < ROWS; ++i)
#pragma unroll
        for (int j = 0; j < 4; ++j) acc[i][j] = fmaf(af[i], bf[j], acc[i][j]);
    }
    __syncthreads();
  }
#pragma unroll
  for (int i = 0; i < ROWS; ++i) {
    int r = row0 + ty * ROWS + i;
    if (r >= n) continue;
    int c = col0 + (tx << 2);
    float4 v;
    v.x = acc[i][0]; v.y = acc[i][1]; v.z = acc[i][2]; v.w = acc[i][3];
    if (bias) { v.x += bias[c]; v.y += bias[c + 1]; v.z += bias[c + 2]; v.w += bias[c + 3]; }
    if (add) {
      const float* ad = add + (size_t)r * FD + c;
      v.x += ad[0]; v.y += ad[1]; v.z += ad[2]; v.w += ad[3];
    }
    *(float4*)(C + (size_t)r * FD + c) = v;
  }
}

static inline unsigned cdiv(int a, int b) { return (unsigned)((a + b - 1) / b); }

static void launch_gemm(const float* A, const float* W, const float* bias, const float* add,
                        float* C, int n, int K, hipStream_t stream) {
  if (n >= 4096)
    gemm_t<128, 8><<<dim3(cdiv(n, 128), 5), dim3(256), 0, stream>>>(A, W, bias, add, C, n, K);
  else
    gemm_t<64, 4><<<dim3(cdiv(n, 64), 5), dim3(256), 0, stream>>>(A, W, bias, add, C, n, K);
}

// ---------------- GAT helpers ----------------
__global__ __launch_bounds__(256) void esed_k(const float* __restrict__ h, const float* __restrict__ a,
                                              float* __restrict__ es, float* __restrict__ ed, int n) {
  int w = blockIdx.x * 4 + (threadIdx.x >> 6);
  int lane = threadIdx.x & 63;
  if (w >= n) return;
  const float* hr = h + (size_t)w * FD;
  const float* a2 = a + FD;
  float sa = 0.f, sb = 0.f;
#pragma unroll
  for (int c = 0; c < 5; ++c) {
    float hv = hr[lane + 64 * c];
    sa += hv * a[lane + 64 * c];
    sb += hv * a2[lane + 64 * c];
  }
  for (int o = 32; o; o >>= 1) { sa += __shfl_xor(sa, o); sb += __shfl_xor(sb, o); }
  if (lane == 0) { es[w] = sa; ed[w] = sb; }
}

// ---------------- pooling ----------------
__global__ __launch_bounds__(256) void score_k(const float* __restrict__ X, const float* __restrict__ pw,
                                               const float* __restrict__ pb, float* __restrict__ sc, int n) {
  int w = blockIdx.x * 4 + (threadIdx.x >> 6);
  int lane = threadIdx.x & 63;
  if (w >= n) return;
  const float* xr = X + (size_t)w * FD;
  float s = 0.f;
#pragma unroll
  for (int c = 0; c < 5; ++c) s += xr[lane + 64 * c] * pw[lane + 64 * c];
  for (int o = 32; o; o >>= 1) s += __shfl_xor(s, o);
  if (lane == 0) {
    float u = (s + pb[0]) / 100.0f;
    sc[w] = 1.0f / (1.0f + expf(-u));
  }
}

// single-block bitonic sort, descending by (score_bits, ~index) packed u64.
__global__ __launch_bounds__(1024) void topk_sort_k(const float* __restrict__ scores, int n,
                                                    int* __restrict__ idx_out, float* __restrict__ vals_out, int k) {
  __shared__ unsigned long long s[SORTN];
  int t = threadIdx.x;
  for (int i = t; i < SORTN; i += 1024) {
    unsigned long long key = 0ull;
    if (i < n) {
      unsigned int sb = __float_as_uint(scores[i]);
      key = ((unsigned long long)sb << 32) | (unsigned int)(~i);
    }
    s[i] = key;
  }
  __syncthreads();
  for (int kk = 2; kk <= SORTN; kk <<= 1) {
    for (int j = kk >> 1; j > 0; j >>= 1) {
      for (int i = t; i < SORTN; i += 1024) {
        int p = i ^ j;
        if (p > i) {
          unsigned long long a = s[i], b = s[p];
          bool descend = ((i & kk) == 0);
          bool sw = descend ? (a < b) : (a > b);
          if (sw) { s[i] = b; s[p] = a; }
        }
      }
      __syncthreads();
    }
  }
  for (int i = t; i < k; i += 1024) {
    unsigned long long key = s[i];
    idx_out[i] = (int)(~((unsigned int)key));
    vals_out[i] = __uint_as_float((unsigned int)(key >> 32));
  }
}

__global__ void fill_i32_k(int* __restrict__ p, int v, int n) {
  int i = blockIdx.x * 256 + threadIdx.x;
  if (i < n) p[i] = v;
}
__global__ void scatter_inv_k(const int* __restrict__ idx, int* __restrict__ inv, int k) {
  int i = blockIdx.x * 256 + threadIdx.x;
  if (i < k) inv[idx[i]] = i;
}
__global__ void gather_scale_k(const float* __restrict__ X, const int* __restrict__ idx,
                               const float* __restrict__ vals, float* __restrict__ out, int k) {
  int i = blockIdx.x * 256 + threadIdx.x;
  if (i >= k * FD) return;
  int r = i / FD, c = i - r * FD;
  out[i] = X[(size_t)idx[r] * FD + c] * vals[r];
}
__global__ void concat_k(const float* __restrict__ Xa, const float* __restrict__ Xb,
                         float* __restrict__ out, int n) {
  int i = blockIdx.x * 256 + threadIdx.x;
  if (i >= n * 2 * FD) return;
  int r = i / (2 * FD), c = i - r * 2 * FD;
  out[i] = (c < FD) ? Xa[(size_t)r * FD + c] : Xb[(size_t)r * FD + (c - FD)];
}

// ---------------- host ----------------
static inline dim3 wgrid(int n) { return dim3((unsigned)((n + 3) / 4)); }

extern "C" void kernel_launch(void* const* d_in, const int* in_sizes, int n_in,
                              void* d_out, int out_size, void* d_ws, size_t ws_size,
                              hipStream_t stream) {
  const float* A      = (const float*)d_in[0];
  const float* X0     = (const float*)d_in[1];
  const float* sg_W   = (const float*)d_in[2];
  const float* sg_a   = (const float*)d_in[3];
  const float* bg_W   = (const float*)d_in[4];
  const float* bg_a   = (const float*)d_in[5];
  const float* eg_W   = (const float*)d_in[6];
  const float* eg_a   = (const float*)d_in[7];
  const float* down_W = (const float*)d_in[8];
  const float* down_b = (const float*)d_in[9];
  const float* up_W   = (const float*)d_in[10];
  const float* up_b   = (const float*)d_in[11];
  const float* pool_w = (const float*)d_in[12];
  const float* pool_b = (const float*)d_in[13];
  float* out = (float*)d_out;
  char* ws = (char*)d_ws;

  size_t off = 0;
  auto alloc = [&](size_t bytes) -> char* {
    char* p = ws + off;
    off += (bytes + 255) & ~(size_t)255;
    return p;
  };
  int* adj0  = (int*)alloc((size_t)N0 * CAP * 4);
  int* deg0  = (int*)alloc((size_t)N0 * 4);
  int* adj1a = (int*)alloc((size_t)NN1 * CAP * 4);
  int* deg1a = (int*)alloc((size_t)NN1 * 4);
  int* adj1b = (int*)alloc((size_t)NN1 * CAP * 4);
  int* deg1b = (int*)alloc((size_t)NN1 * 4);
  int* adj2  = (int*)alloc((size_t)NN2 * CAP * 4);
  int* deg2  = (int*)alloc((size_t)NN2 * 4);
  int* inv0a = (int*)alloc((size_t)N0 * 4);
  int* inv0b = (int*)alloc((size_t)N0 * 4);
  int* inv1a = (int*)alloc((size_t)NN1 * 4);
  int* inv1b = (int*)alloc((size_t)NN1 * 4);
  int* idx0a = (int*)alloc((size_t)NN1 * 4);
  int* idx0b = (int*)alloc((size_t)NN1 * 4);
  int* idx1a = (int*)alloc((size_t)NN2 * 4);
  int* idx1b = (int*)alloc((size_t)NN2 * 4);
  float* scores = (float*)alloc((size_t)N0 * 4);
  float* vals   = (float*)alloc((size_t)N0 * 4);
  float* es     = (float*)alloc((size_t)N0 * 4);
  float* ed     = (float*)alloc((size_t)N0 * 4);
  float* hbuf   = (float*)alloc((size_t)N0 * FD * 4);
  float* S      = (float*)alloc((size_t)N0 * FD * 4);
  float* Xcur   = (float*)alloc((size_t)N0 * FD * 4);
  float* d0a    = (float*)alloc((size_t)N0 * FD * 4);
  float* d1a    = (float*)alloc((size_t)NN1 * FD * 4);
  float* d0b    = (float*)alloc((size_t)N0 * FD * 4);
  float* d1b    = (float*)alloc((size_t)NN1 * FD * 4);
  float* Xp1    = (float*)alloc((size_t)NN1 * FD * 4);
  float* Xp2    = (float*)alloc((size_t)NN2 * FD * 4);
  float* Xb     = (float*)alloc((size_t)NN2 * FD * 4);
  float* Xu1    = (float*)alloc((size_t)NN1 * FD * 4);
  float* Xu0    = (float*)alloc((size_t)N0 * FD * 4);
  float* Xc     = (float*)alloc((size_t)N0 * 2 * FD * 4);

  dim3 b256(256), b1024(1024);

  build_adj_k<<<wgrid(N0), b256, 0, stream>>>(A, adj0, deg0);

  // sg GAT -> start (second half of d_out), also serves as org_X
  float* orgX = out + (size_t)N0 * FD;
  launch_gemm(X0, sg_W, nullptr, nullptr, hbuf, N0, FD, stream);
  esed_k<<<wgrid(N0), b256, 0, stream>>>(hbuf, sg_a, es, ed, N0);
  gat_k<<<wgrid(N0), b256, 0, stream>>>(adj0, deg0, hbuf, es, ed, orgX, N0);

  const float* Xin = orgX;
  for (int pass = 0; pass < 2; ++pass) {
    int* idx0p = pass ? idx0b : idx0a;
    int* inv0p = pass ? inv0b : inv0a;
    int* idx1p = pass ? idx1b : idx1a;
    int* inv1p = pass ? inv1b : inv1a;
    int* adj1p = pass ? adj1b : adj1a;
    int* deg1p = pass ? deg1b : deg1a;
    float* d0p = pass ? d0b : d0a;
    float* d1p = pass ? d1b : d1a;

    // ---- down level 0 (n = N0) ----
    spmm_k<<<wgrid(N0), b256, 0, stream>>>(adj0, deg0, Xin, S, N0);
    launch_gemm(S, down_W, down_b, nullptr, d0p, N0, FD, stream);
    score_k<<<wgrid(N0), b256, 0, stream>>>(d0p, pool_w, pool_b, scores, N0);
    topk_sort_k<<<dim3(1), b1024, 0, stream>>>(scores, N0, idx0p, vals, NN1);
    fill_i32_k<<<cdiv(N0, 256), b256, 0, stream>>>(inv0p, -1, N0);
    scatter_inv_k<<<cdiv(NN1, 256), b256, 0, stream>>>(idx0p, inv0p, NN1);
    gather_scale_k<<<cdiv(NN1 * FD, 256), b256, 0, stream>>>(d0p, idx0p, vals, Xp1, NN1);
    sub_adj_k<<<wgrid(NN1), b256, 0, stream>>>(adj0, deg0, idx0p, inv0p, adj1p, deg1p, NN1);

    // ---- down level 1 (n = NN1) ----
    spmm_k<<<wgrid(NN1), b256, 0, stream>>>(adj1p, deg1p, Xp1, S, NN1);
    launch_gemm(S, down_W + FD * FD, down_b + FD, nullptr, d1p, NN1, FD, stream);
    score_k<<<wgrid(NN1), b256, 0, stream>>>(d1p, pool_w + FD, pool_b + 1, scores, NN1);
    topk_sort_k<<<dim3(1), b1024, 0, stream>>>(scores, NN1, idx1p, vals, NN2);
    fill_i32_k<<<cdiv(NN1, 256), b256, 0, stream>>>(inv1p, -1, NN1);
    scatter_inv_k<<<cdiv(NN2, 256), b256, 0, stream>>>(idx1p, inv1p, NN2);
    gather_scale_k<<<cdiv(NN2 * FD, 256), b256, 0, stream>>>(d1p, idx1p, vals, Xp2, NN2);
    sub_adj_k<<<wgrid(NN2), b256, 0, stream>>>(adj1p, deg1p, idx1p, inv1p, adj2, deg2, NN2);

    // ---- bottom GAT (n = NN2) ----
    launch_gemm(Xp2, bg_W, nullptr, nullptr, hbuf, NN2, FD, stream);
    esed_k<<<wgrid(NN2), b256, 0, stream>>>(hbuf, bg_a, es, ed, NN2);
    gat_k<<<wgrid(NN2), b256, 0, stream>>>(adj2, deg2, hbuf, es, ed, Xb, NN2);

    // ---- up path: ALWAYS pass-1 ("a") graph state, per reference indexing ----
    mspmm_k<<<wgrid(NN1), b256, 0, stream>>>(adj1a, deg1a, inv1a, Xb, S, NN1);
    launch_gemm(S, up_W, up_b, d1a, Xu1, NN1, FD, stream);
    mspmm_k<<<wgrid(N0), b256, 0, stream>>>(adj0, deg0, inv0a, Xu1, S, N0);
    launch_gemm(S, up_W + FD * FD, up_b + FD, d0a, Xu0, N0, FD, stream);

    // ---- end GAT on concat([Xu0, org_X]) (n = N0, K = 640) ----
    concat_k<<<cdiv(N0 * 2 * FD, 256), b256, 0, stream>>>(Xu0, orgX, Xc, N0);
    launch_gemm(Xc, eg_W, nullptr, nullptr, hbuf, N0, 2 * FD, stream);
    esed_k<<<wgrid(N0), b256, 0, stream>>>(hbuf, eg_a, es, ed, N0);
    float* egout = pass ? out : Xcur;
    gat_k<<<wgrid(N0), b256, 0, stream>>>(adj0, deg0, hbuf, es, ed, egout, N0);
    Xin = egout;
  }
}

// Round 3
// 1698.129 us; speedup vs baseline: 1.5006x; 1.2379x over previous
//
#include <hip/hip_runtime.h>
#include <cstdint>
#include <cmath>

#define N0   6144
#define FD   320
#define NN1  4915
#define NN2  2949
#define CAP  384

// ---------------- adjacency build: dense row -> compact column list ----------------
__global__ __launch_bounds__(256) void build_adj_k(const float* __restrict__ A,
                                                   int* __restrict__ adj, int* __restrict__ deg) {
  int w = blockIdx.x * 4 + (threadIdx.x >> 6);
  int lane = threadIdx.x & 63;
  if (w >= N0) return;
  const float* row = A + (size_t)w * N0;
  int* dst = adj + (size_t)w * CAP;
  int base = 0;
  for (int j0 = 0; j0 < N0; j0 += 64) {
    float v = row[j0 + lane];
    unsigned long long m = __ballot(v > 0.0f);
    if (v > 0.0f) dst[base + __popcll(m & ((1ull << lane) - 1ull))] = j0 + lane;
    base += (int)__popcll(m);
  }
  if (lane == 0) deg[w] = base;
}

// subgraph adjacency: new row r <- old row idx[r], keep cols with inv[c]>=0, renumber
__global__ __launch_bounds__(256) void sub_adj_k(const int* __restrict__ adjs, const int* __restrict__ degs,
                                                 const int* __restrict__ idx, const int* __restrict__ inv,
                                                 int* __restrict__ adjd, int* __restrict__ degd, int k) {
  int w = blockIdx.x * 4 + (threadIdx.x >> 6);
  int lane = threadIdx.x & 63;
  if (w >= k) return;
  int o = idx[w];
  int d = degs[o];
  const int* src = adjs + (size_t)o * CAP;
  int* dst = adjd + (size_t)w * CAP;
  int base = 0;
  for (int t0 = 0; t0 < d; t0 += 64) {
    int tt = t0 + lane;
    int p = -1;
    if (tt < d) p = inv[src[tt]];
    unsigned long long m = __ballot(p >= 0);
    if (p >= 0) dst[base + __popcll(m & ((1ull << lane) - 1ull))] = p;
    base += (int)__popcll(m);
  }
  if (lane == 0) degd[w] = base;
}

// ================= tiled gather family =================
#define GATHER_CORE(XSRC)                                                        \
  int sub = lane & 15, g = lane >> 4;                                            \
  float4 a0 = {0,0,0,0}, a1 = {0,0,0,0}, a2 = {0,0,0,0}, a3 = {0,0,0,0}, a4 = {0,0,0,0}; \
  _Pragma("unroll 2")                                                            \
  for (int t = 0; t < d; t += 4) {                                               \
    int jj = lj[t + g];                                                          \
    float ww = lw[t + g];                                                        \
    const float* base = XSRC + (size_t)jj * FD + (sub << 2);                     \
    float4 v0 = *(const float4*)(base);                                          \
    float4 v1 = *(const float4*)(base + 64);                                     \
    float4 v2 = *(const float4*)(base + 128);                                    \
    float4 v3 = *(const float4*)(base + 192);                                    \
    float4 v4 = *(const float4*)(base + 256);                                    \
    a0.x = fmaf(ww, v0.x, a0.x); a0.y = fmaf(ww, v0.y, a0.y);                    \
    a0.z = fmaf(ww, v0.z, a0.z); a0.w = fmaf(ww, v0.w, a0.w);                    \
    a1.x = fmaf(ww, v1.x, a1.x); a1.y = fmaf(ww, v1.y, a1.y);                    \
    a1.z = fmaf(ww, v1.z, a1.z); a1.w = fmaf(ww, v1.w, a1.w);                    \
    a2.x = fmaf(ww, v2.x, a2.x); a2.y = fmaf(ww, v2.y, a2.y);                    \
    a2.z = fmaf(ww, v2.z, a2.z); a2.w = fmaf(ww, v2.w, a2.w);                    \
    a3.x = fmaf(ww, v3.x, a3.x); a3.y = fmaf(ww, v3.y, a3.y);                    \
    a3.z = fmaf(ww, v3.z, a3.z); a3.w = fmaf(ww, v3.w, a3.w);                    \
    a4.x = fmaf(ww, v4.x, a4.x); a4.y = fmaf(ww, v4.y, a4.y);                    \
    a4.z = fmaf(ww, v4.z, a4.z); a4.w = fmaf(ww, v4.w, a4.w);                    \
  }                                                                              \
  _Pragma("unroll")                                                              \
  for (int off = 16; off <= 32; off <<= 1) {                                     \
    a0.x += __shfl_xor(a0.x, off); a0.y += __shfl_xor(a0.y, off);                \
    a0.z += __shfl_xor(a0.z, off); a0.w += __shfl_xor(a0.w, off);                \
    a1.x += __shfl_xor(a1.x, off); a1.y += __shfl_xor(a1.y, off);                \
    a1.z += __shfl_xor(a1.z, off); a1.w += __shfl_xor(a1.w, off);                \
    a2.x += __shfl_xor(a2.x, off); a2.y += __shfl_xor(a2.y, off);                \
    a2.z += __shfl_xor(a2.z, off); a2.w += __shfl_xor(a2.w, off);                \
    a3.x += __shfl_xor(a3.x, off); a3.y += __shfl_xor(a3.y, off);                \
    a3.z += __shfl_xor(a3.z, off); a3.w += __shfl_xor(a3.w, off);                \
    a4.x += __shfl_xor(a4.x, off); a4.y += __shfl_xor(a4.y, off);                \
    a4.z += __shfl_xor(a4.z, off); a4.w += __shfl_xor(a4.w, off);                \
  }                                                                              \
  float4 osel = (g == 0) ? a0 : (g == 1) ? a1 : (g == 2) ? a2 : a3;

// Y[r,:] = sum_{j in N(r)} X[j,:]
__global__ __launch_bounds__(256) void spmm_k(const int* __restrict__ adj, const int* __restrict__ deg,
                                              const float* __restrict__ X, float* __restrict__ Y, int n) {
  __shared__ int ljs[4][CAP];
  __shared__ float lws[4][CAP];
  int wv = threadIdx.x >> 6, lane = threadIdx.x & 63;
  int w = blockIdx.x * 4 + wv;
  if (w >= n) return;
  int* lj = ljs[wv]; float* lw = lws[wv];
  int d = deg[w];
  const int* row = adj + (size_t)w * CAP;
  for (int t0 = 0; t0 < d; t0 += 64) {
    int tt = t0 + lane;
    lj[tt] = (tt < d) ? row[tt] : 0;
    lw[tt] = (tt < d) ? 1.0f : 0.0f;
  }
  GATHER_CORE(X)
  float* yr = Y + (size_t)w * FD;
  *(float4*)(yr + g * 64 + (sub << 2)) = osel;
  if (g == 0) *(float4*)(yr + 256 + (sub << 2)) = a4;
}

// fused unpool + A@Xn: source row = inv[col] into pooled X, skip if -1
__global__ __launch_bounds__(256) void mspmm_k(const int* __restrict__ adj, const int* __restrict__ deg,
                                               const int* __restrict__ inv,
                                               const float* __restrict__ Xp, float* __restrict__ Y, int n) {
  __shared__ int ljs[4][CAP];
  __shared__ float lws[4][CAP];
  int wv = threadIdx.x >> 6, lane = threadIdx.x & 63;
  int w = blockIdx.x * 4 + wv;
  if (w >= n) return;
  int* lj = ljs[wv]; float* lw = lws[wv];
  int d = deg[w];
  const int* row = adj + (size_t)w * CAP;
  for (int t0 = 0; t0 < d; t0 += 64) {
    int tt = t0 + lane;
    int p = -1;
    if (tt < d) p = inv[row[tt]];
    lj[tt] = p >= 0 ? p : 0;
    lw[tt] = p >= 0 ? 1.0f : 0.0f;
  }
  GATHER_CORE(Xp)
  float* yr = Y + (size_t)w * FD;
  *(float4*)(yr + g * 64 + (sub << 2)) = osel;
  if (g == 0) *(float4*)(yr + 256 + (sub << 2)) = a4;
}

// fused masked-softmax GAT row: out = elu( softmax_edges(LR(es_i+ed_j)) @ h )
__global__ __launch_bounds__(256) void gat_k(const int* __restrict__ adj, const int* __restrict__ deg,
                                             const float* __restrict__ h, const float* __restrict__ es,
                                             const float* __restrict__ ed, float* __restrict__ out, int n) {
  __shared__ int ljs[4][CAP];
  __shared__ float lws[4][CAP];
  int wv = threadIdx.x >> 6, lane = threadIdx.x & 63;
  int w = blockIdx.x * 4 + wv;
  if (w >= n) return;
  int* lj = ljs[wv]; float* lw = lws[wv];
  int d = deg[w];
  const int* row = adj + (size_t)w * CAP;
  float esr = es[w];
  float m = -INFINITY;
  for (int t0 = 0; t0 < d; t0 += 64) {
    int tt = t0 + lane;
    int j = (tt < d) ? row[tt] : 0;
    float e = -INFINITY;
    if (tt < d) {
      e = esr + ed[j];
      e = e >= 0.f ? e : 0.2f * e;
    }
    lj[tt] = j;
    lw[tt] = e;
    m = fmaxf(m, e);
  }
  #pragma unroll
  for (int off = 32; off; off >>= 1) m = fmaxf(m, __shfl_xor(m, off));
  float zacc = 0.f;
  for (int t0 = 0; t0 < d; t0 += 64) {
    int tt = t0 + lane;
    float wgt = expf(lw[tt] - m);
    lw[tt] = wgt;
    zacc += wgt;
  }
  #pragma unroll
  for (int off = 32; off; off >>= 1) zacc += __shfl_xor(zacc, off);
  GATHER_CORE(h)
  float* yr = out + (size_t)w * FD;
  float4 o;
  o.x = osel.x / zacc; o.y = osel.y / zacc; o.z = osel.z / zacc; o.w = osel.w / zacc;
  o.x = o.x > 0.f ? o.x : expm1f(o.x);
  o.y = o.y > 0.f ? o.y : expm1f(o.y);
  o.z = o.z > 0.f ? o.z : expm1f(o.z);
  o.w = o.w > 0.f ? o.w : expm1f(o.w);
  *(float4*)(yr + g * 64 + (sub << 2)) = o;
  if (g == 0) {
    float4 o4;
    o4.x = a4.x / zacc; o4.y = a4.y / zacc; o4.z = a4.z / zacc; o4.w = a4.w / zacc;
    o4.x = o4.x > 0.f ? o4.x : expm1f(o4.x);
    o4.y = o4.y > 0.f ? o4.y : expm1f(o4.y);
    o4.z = o4.z > 0.f ? o4.z : expm1f(o4.z);
    o4.w = o4.w > 0.f ? o4.w : expm1f(o4.w);
    *(float4*)(yr + 256 + (sub << 2)) = o4;
  }
}

// ---------------- fp32 tiled GEMM ----------------
template<int BM, int ROWS>
__global__ __launch_bounds__(256) void gemm_t(const float* __restrict__ A, const float* __restrict__ W,
                                              const float* __restrict__ bias, const float* __restrict__ add,
                                              float* __restrict__ C, int n, int K) {
  __shared__ float As[16][BM + 4];
  __shared__ float Bs[16][68];
  int t = threadIdx.x;
  int tx = t & 15, ty = t >> 4;
  int row0 = blockIdx.x * BM, col0 = blockIdx.y * 64;
  float acc[ROWS][4] = {};
  int ar = t >> 2;
  int ak = (t & 3) << 2;
  int bk = t >> 4;
  int bc = (t & 15) << 2;
  for (int k0 = 0; k0 < K; k0 += 16) {
#pragma unroll
    for (int rr = 0; rr < BM; rr += 64) {
      int r = ar + rr;
      float4 av = make_float4(0.f, 0.f, 0.f, 0.f);
      int grow = row0 + r;
      if (grow < n) av = *(const float4*)(A + (size_t)grow * K + k0 + ak);
      As[ak + 0][r] = av.x; As[ak + 1][r] = av.y; As[ak + 2][r] = av.z; As[ak + 3][r] = av.w;
    }
    float4 bv = *(const float4*)(W + (size_t)(k0 + bk) * FD + col0 + bc);
    *(float4*)&Bs[bk][bc] = bv;
    __syncthreads();
#pragma unroll
    for (int kk = 0; kk < 16; ++kk) {
      float bf[4];
      *(float4*)bf = *(const float4*)&Bs[kk][tx << 2];
      float af[ROWS];
#pragma unroll
      for (int i = 0; i < ROWS; i += 4) *(float4*)(af + i) = *(const float4*)&As[kk][ty * ROWS + i];
#pragma unroll
      for (int i = 0; i < ROWS; ++i)
#pragma unroll
        for (int j = 0; j < 4; ++j) acc[i][j] = fmaf(af[i], bf[j], acc[i][j]);
    }
    __syncthreads();
  }
#pragma unroll
  for (int i = 0; i < ROWS; ++i) {
    int r = row0 + ty * ROWS + i;
    if (r >= n) continue;
    int c = col0 + (tx << 2);
    float4 v;
    v.x = acc[i][0]; v.y = acc[i][1]; v.z = acc[i][2]; v.w = acc[i][3];
    if (bias) { v.x += bias[c]; v.y += bias[c + 1]; v.z += bias[c + 2]; v.w += bias[c + 3]; }
    if (add) {
      const float* ad = add + (size_t)r * FD + c;
      v.x += ad[0]; v.y += ad[1]; v.z += ad[2]; v.w += ad[3];
    }
    *(float4*)(C + (size_t)r * FD + c) = v;
  }
}

static inline unsigned cdiv(int a, int b) { return (unsigned)((a + b - 1) / b); }

static void launch_gemm(const float* A, const float* W, const float* bias, const float* add,
                        float* C, int n, int K, hipStream_t stream) {
  if (n >= 4096)
    gemm_t<128, 8><<<dim3(cdiv(n, 128), 5), dim3(256), 0, stream>>>(A, W, bias, add, C, n, K);
  else
    gemm_t<64, 4><<<dim3(cdiv(n, 64), 5), dim3(256), 0, stream>>>(A, W, bias, add, C, n, K);
}

// ---------------- GAT helpers ----------------
__global__ __launch_bounds__(256) void esed_k(const float* __restrict__ h, const float* __restrict__ a,
                                              float* __restrict__ es, float* __restrict__ ed, int n) {
  int w = blockIdx.x * 4 + (threadIdx.x >> 6);
  int lane = threadIdx.x & 63;
  if (w >= n) return;
  const float* hr = h + (size_t)w * FD;
  const float* a2 = a + FD;
  float sa = 0.f, sb = 0.f;
#pragma unroll
  for (int c = 0; c < 5; ++c) {
    float hv = hr[lane + 64 * c];
    sa += hv * a[lane + 64 * c];
    sb += hv * a2[lane + 64 * c];
  }
  for (int o = 32; o; o >>= 1) { sa += __shfl_xor(sa, o); sb += __shfl_xor(sb, o); }
  if (lane == 0) { es[w] = sa; ed[w] = sb; }
}

// ---------------- pooling ----------------
__global__ __launch_bounds__(256) void score_k(const float* __restrict__ X, const float* __restrict__ pw,
                                               const float* __restrict__ pb, float* __restrict__ sc, int n) {
  int w = blockIdx.x * 4 + (threadIdx.x >> 6);
  int lane = threadIdx.x & 63;
  if (w >= n) return;
  const float* xr = X + (size_t)w * FD;
  float s = 0.f;
#pragma unroll
  for (int c = 0; c < 5; ++c) s += xr[lane + 64 * c] * pw[lane + 64 * c];
  for (int o = 32; o; o >>= 1) s += __shfl_xor(s, o);
  if (lane == 0) {
    float u = (s + pb[0]) / 100.0f;
    sc[w] = 1.0f / (1.0f + expf(-u));
  }
}

// ---------------- rank-based exact descending top-k ----------------
// keys are distinct by construction: (score_bits << 32) | ~i.
// rank[i] = #{j : key_j > key_i} is a perfect permutation matching
// jax.lax.top_k order (descending score, ascending index on bit-ties).
__global__ __launch_bounds__(256) void key_build_k(const float* __restrict__ scores,
                                                   unsigned long long* __restrict__ keys, int n) {
  int i = blockIdx.x * 256 + threadIdx.x;
  if (i >= n) return;
  unsigned int sb = __float_as_uint(scores[i]);   // sigmoid > 0: monotone as uint
  keys[i] = ((unsigned long long)sb << 32) | (unsigned int)(~i);
}

#define RANK_TILE 1024
__global__ __launch_bounds__(256) void rank_count_k(const unsigned long long* __restrict__ keys,
                                                    int n, int jchunk, int* __restrict__ rank) {
  __shared__ unsigned long long tile[RANK_TILE];
  int i = blockIdx.x * 256 + threadIdx.x;
  unsigned long long my = (i < n) ? keys[i] : 0ull;
  int j0 = blockIdx.y * jchunk;
  int jend = j0 + jchunk; if (jend > n) jend = n;
  int cnt = 0;
  for (int t0 = j0; t0 < jend; t0 += RANK_TILE) {
    int m = jend - t0; if (m > RANK_TILE) m = RANK_TILE;
    for (int t = threadIdx.x; t < m; t += 256) tile[t] = keys[t0 + t];
    __syncthreads();
    for (int t = 0; t < m; ++t) cnt += (tile[t] > my) ? 1 : 0;
    __syncthreads();
  }
  if (i < n && cnt) atomicAdd(&rank[i], cnt);
}

__global__ __launch_bounds__(256) void rank_scatter_k(const float* __restrict__ scores,
                                                      const int* __restrict__ rank, int n, int k,
                                                      int* __restrict__ idx_out, float* __restrict__ vals_out) {
  int i = blockIdx.x * 256 + threadIdx.x;
  if (i >= n) return;
  int r = rank[i];
  if (r < k) { idx_out[r] = i; vals_out[r] = scores[i]; }
}

__global__ void fill_i32_k(int* __restrict__ p, int v, int n) {
  int i = blockIdx.x * 256 + threadIdx.x;
  if (i < n) p[i] = v;
}
__global__ void scatter_inv_k(const int* __restrict__ idx, int* __restrict__ inv, int k) {
  int i = blockIdx.x * 256 + threadIdx.x;
  if (i < k) inv[idx[i]] = i;
}
__global__ void gather_scale_k(const float* __restrict__ X, const int* __restrict__ idx,
                               const float* __restrict__ vals, float* __restrict__ out, int k) {
  int i = blockIdx.x * 256 + threadIdx.x;
  if (i >= k * FD) return;
  int r = i / FD, c = i - r * FD;
  out[i] = X[(size_t)idx[r] * FD + c] * vals[r];
}
__global__ void concat_k(const float* __restrict__ Xa, const float* __restrict__ Xb,
                         float* __restrict__ out, int n) {
  int i = blockIdx.x * 256 + threadIdx.x;
  if (i >= n * 2 * FD) return;
  int r = i / (2 * FD), c = i - r * 2 * FD;
  out[i] = (c < FD) ? Xa[(size_t)r * FD + c] : Xb[(size_t)r * FD + (c - FD)];
}

// ---------------- host ----------------
static inline dim3 wgrid(int n) { return dim3((unsigned)((n + 3) / 4)); }

struct TopkBufs { unsigned long long* keys; int* rank; };

static void launch_topk(const float* scores, int n, int k, int* idx_out, float* vals_out,
                        TopkBufs tb, hipStream_t stream) {
  key_build_k<<<cdiv(n, 256), dim3(256), 0, stream>>>(scores, tb.keys, n);
  fill_i32_k<<<cdiv(n, 256), dim3(256), 0, stream>>>(tb.rank, 0, n);
  const int JS = 8;
  int jchunk = (n + JS - 1) / JS;
  rank_count_k<<<dim3(cdiv(n, 256), JS), dim3(256), 0, stream>>>(tb.keys, n, jchunk, tb.rank);
  rank_scatter_k<<<cdiv(n, 256), dim3(256), 0, stream>>>(scores, tb.rank, n, k, idx_out, vals_out);
}

extern "C" void kernel_launch(void* const* d_in, const int* in_sizes, int n_in,
                              void* d_out, int out_size, void* d_ws, size_t ws_size,
                              hipStream_t stream) {
  const float* A      = (const float*)d_in[0];
  const float* X0     = (const float*)d_in[1];
  const float* sg_W   = (const float*)d_in[2];
  const float* sg_a   = (const float*)d_in[3];
  const float* bg_W   = (const float*)d_in[4];
  const float* bg_a   = (const float*)d_in[5];
  const float* eg_W   = (const float*)d_in[6];
  const float* eg_a   = (const float*)d_in[7];
  const float* down_W = (const float*)d_in[8];
  const float* down_b = (const float*)d_in[9];
  const float* up_W   = (const float*)d_in[10];
  const float* up_b   = (const float*)d_in[11];
  const float* pool_w = (const float*)d_in[12];
  const float* pool_b = (const float*)d_in[13];
  float* out = (float*)d_out;
  char* ws = (char*)d_ws;

  size_t off = 0;
  auto alloc = [&](size_t bytes) -> char* {
    char* p = ws + off;
    off += (bytes + 255) & ~(size_t)255;
    return p;
  };
  int* adj0  = (int*)alloc((size_t)N0 * CAP * 4);
  int* deg0  = (int*)alloc((size_t)N0 * 4);
  int* adj1a = (int*)alloc((size_t)NN1 * CAP * 4);
  int* deg1a = (int*)alloc((size_t)NN1 * 4);
  int* adj1b = (int*)alloc((size_t)NN1 * CAP * 4);
  int* deg1b = (int*)alloc((size_t)NN1 * 4);
  int* adj2  = (int*)alloc((size_t)NN2 * CAP * 4);
  int* deg2  = (int*)alloc((size_t)NN2 * 4);
  int* inv0a = (int*)alloc((size_t)N0 * 4);
  int* inv0b = (int*)alloc((size_t)N0 * 4);
  int* inv1a = (int*)alloc((size_t)NN1 * 4);
  int* inv1b = (int*)alloc((size_t)NN1 * 4);
  int* idx0a = (int*)alloc((size_t)NN1 * 4);
  int* idx0b = (int*)alloc((size_t)NN1 * 4);
  int* idx1a = (int*)alloc((size_t)NN2 * 4);
  int* idx1b = (int*)alloc((size_t)NN2 * 4);
  unsigned long long* keys = (unsigned long long*)alloc((size_t)N0 * 8);
  int* rankb = (int*)alloc((size_t)N0 * 4);
  float* scores = (float*)alloc((size_t)N0 * 4);
  float* vals   = (float*)alloc((size_t)N0 * 4);
  float* es     = (float*)alloc((size_t)N0 * 4);
  float* ed     = (float*)alloc((size_t)N0 * 4);
  float* hbuf   = (float*)alloc((size_t)N0 * FD * 4);
  float* S      = (float*)alloc((size_t)N0 * FD * 4);
  float* Xcur   = (float*)alloc((size_t)N0 * FD * 4);
  float* d0a    = (float*)alloc((size_t)N0 * FD * 4);
  float* d1a    = (float*)alloc((size_t)NN1 * FD * 4);
  float* d0b    = (float*)alloc((size_t)N0 * FD * 4);
  float* d1b    = (float*)alloc((size_t)NN1 * FD * 4);
  float* Xp1    = (float*)alloc((size_t)NN1 * FD * 4);
  float* Xp2    = (float*)alloc((size_t)NN2 * FD * 4);
  float* Xb     = (float*)alloc((size_t)NN2 * FD * 4);
  float* Xu1    = (float*)alloc((size_t)NN1 * FD * 4);
  float* Xu0    = (float*)alloc((size_t)N0 * FD * 4);
  float* Xc     = (float*)alloc((size_t)N0 * 2 * FD * 4);

  TopkBufs tb{keys, rankb};
  dim3 b256(256);

  build_adj_k<<<wgrid(N0), b256, 0, stream>>>(A, adj0, deg0);

  float* orgX = out + (size_t)N0 * FD;
  launch_gemm(X0, sg_W, nullptr, nullptr, hbuf, N0, FD, stream);
  esed_k<<<wgrid(N0), b256, 0, stream>>>(hbuf, sg_a, es, ed, N0);
  gat_k<<<wgrid(N0), b256, 0, stream>>>(adj0, deg0, hbuf, es, ed, orgX, N0);

  const float* Xin = orgX;
  for (int pass = 0; pass < 2; ++pass) {
    int* idx0p = pass ? idx0b : idx0a;
    int* inv0p = pass ? inv0b : inv0a;
    int* idx1p = pass ? idx1b : idx1a;
    int* inv1p = pass ? inv1b : inv1a;
    int* adj1p = pass ? adj1b : adj1a;
    int* deg1p = pass ? deg1b : deg1a;
    float* d0p = pass ? d0b : d0a;
    float* d1p = pass ? d1b : d1a;

    // ---- down level 0 (n = N0) ----
    spmm_k<<<wgrid(N0), b256, 0, stream>>>(adj0, deg0, Xin, S, N0);
    launch_gemm(S, down_W, down_b, nullptr, d0p, N0, FD, stream);
    score_k<<<wgrid(N0), b256, 0, stream>>>(d0p, pool_w, pool_b, scores, N0);
    launch_topk(scores, N0, NN1, idx0p, vals, tb, stream);
    fill_i32_k<<<cdiv(N0, 256), b256, 0, stream>>>(inv0p, -1, N0);
    scatter_inv_k<<<cdiv(NN1, 256), b256, 0, stream>>>(idx0p, inv0p, NN1);
    gather_scale_k<<<cdiv(NN1 * FD, 256), b256, 0, stream>>>(d0p, idx0p, vals, Xp1, NN1);
    sub_adj_k<<<wgrid(NN1), b256, 0, stream>>>(adj0, deg0, idx0p, inv0p, adj1p, deg1p, NN1);

    // ---- down level 1 (n = NN1) ----
    spmm_k<<<wgrid(NN1), b256, 0, stream>>>(adj1p, deg1p, Xp1, S, NN1);
    launch_gemm(S, down_W + FD * FD, down_b + FD, nullptr, d1p, NN1, FD, stream);
    score_k<<<wgrid(NN1), b256, 0, stream>>>(d1p, pool_w + FD, pool_b + 1, scores, NN1);
    launch_topk(scores, NN1, NN2, idx1p, vals, tb, stream);
    fill_i32_k<<<cdiv(NN1, 256), b256, 0, stream>>>(inv1p, -1, NN1);
    scatter_inv_k<<<cdiv(NN2, 256), b256, 0, stream>>>(idx1p, inv1p, NN2);
    gather_scale_k<<<cdiv(NN2 * FD, 256), b256, 0, stream>>>(d1p, idx1p, vals, Xp2, NN2);
    sub_adj_k<<<wgrid(NN2), b256, 0, stream>>>(adj1p, deg1p, idx1p, inv1p, adj2, deg2, NN2);

    // ---- bottom GAT (n = NN2) ----
    launch_gemm(Xp2, bg_W, nullptr, nullptr, hbuf, NN2, FD, stream);
    esed_k<<<wgrid(NN2), b256, 0, stream>>>(hbuf, bg_a, es, ed, NN2);
    gat_k<<<wgrid(NN2), b256, 0, stream>>>(adj2, deg2, hbuf, es, ed, Xb, NN2);

    // ---- up path: ALWAYS pass-1 ("a") graph state, per reference indexing ----
    mspmm_k<<<wgrid(NN1), b256, 0, stream>>>(adj1a, deg1a, inv1a, Xb, S, NN1);
    launch_gemm(S, up_W, up_b, d1a, Xu1, NN1, FD, stream);
    mspmm_k<<<wgrid(N0), b256, 0, stream>>>(adj0, deg0, inv0a, Xu1, S, N0);
    launch_gemm(S, up_W + FD * FD, up_b + FD, d0a, Xu0, N0, FD, stream);

    // ---- end GAT on concat([Xu0, org_X]) (n = N0, K = 640) ----
    concat_k<<<cdiv(N0 * 2 * FD, 256), b256, 0, stream>>>(Xu0, orgX, Xc, N0);
    launch_gemm(Xc, eg_W, nullptr, nullptr, hbuf, N0, 2 * FD, stream);
    esed_k<<<wgrid(N0), b256, 0, stream>>>(hbuf, eg_a, es, ed, N0);
    float* egout = pass ? out : Xcur;
    gat_k<<<wgrid(N0), b256, 0, stream>>>(adj0, deg0, hbuf, es, ed, egout, N0);
    Xin = egout;
  }
}

// Round 4
// 1499.878 us; speedup vs baseline: 1.6989x; 1.1322x over previous
//
#include <hip/hip_runtime.h>
#include <cstdint>
#include <cmath>

#define N0   6144
#define FD   320
#define NN1  4915
#define NN2  2949
#define CAP  384

// ---------------- adjacency build: dense row -> compact column list ----------------
// float4 loads, 4 ballots per 256 cols; ascending column order preserved:
// lane L covers cols j0+4L..j0+4L+3, all lanes<L counted first via masked popc.
__global__ __launch_bounds__(256) void build_adj_k(const float* __restrict__ A,
                                                   int* __restrict__ adj, int* __restrict__ deg) {
  int w = blockIdx.x * 4 + (threadIdx.x >> 6);
  int lane = threadIdx.x & 63;
  if (w >= N0) return;
  const float* row = A + (size_t)w * N0;
  int* dst = adj + (size_t)w * CAP;
  int base = 0;
  unsigned long long lm = (1ull << lane) - 1ull;
  for (int j0 = 0; j0 < N0; j0 += 256) {
    float4 v = *(const float4*)(row + j0 + (lane << 2));
    bool f0 = v.x > 0.f, f1 = v.y > 0.f, f2 = v.z > 0.f, f3 = v.w > 0.f;
    unsigned long long m0 = __ballot(f0), m1 = __ballot(f1), m2 = __ballot(f2), m3 = __ballot(f3);
    int p = base + __popcll(m0 & lm) + __popcll(m1 & lm) + __popcll(m2 & lm) + __popcll(m3 & lm);
    int c0 = j0 + (lane << 2);
    if (f0) dst[p++] = c0;
    if (f1) dst[p++] = c0 + 1;
    if (f2) dst[p++] = c0 + 2;
    if (f3) dst[p++] = c0 + 3;
    base += __popcll(m0) + __popcll(m1) + __popcll(m2) + __popcll(m3);
  }
  if (lane == 0) deg[w] = base;
}

// subgraph adjacency: new row r <- old row idx[r], keep cols with inv[c]>=0, renumber
__global__ __launch_bounds__(256) void sub_adj_k(const int* __restrict__ adjs, const int* __restrict__ degs,
                                                 const int* __restrict__ idx, const int* __restrict__ inv,
                                                 int* __restrict__ adjd, int* __restrict__ degd, int k) {
  int w = blockIdx.x * 4 + (threadIdx.x >> 6);
  int lane = threadIdx.x & 63;
  if (w >= k) return;
  int o = idx[w];
  int d = degs[o];
  const int* src = adjs + (size_t)o * CAP;
  int* dst = adjd + (size_t)w * CAP;
  int base = 0;
  for (int t0 = 0; t0 < d; t0 += 64) {
    int tt = t0 + lane;
    int p = -1;
    if (tt < d) p = inv[src[tt]];
    unsigned long long m = __ballot(p >= 0);
    if (p >= 0) dst[base + __popcll(m & ((1ull << lane) - 1ull))] = p;
    base += (int)__popcll(m);
  }
  if (lane == 0) degd[w] = base;
}

// ================= tiled gather family =================
#define GATHER_CORE(XSRC)                                                        \
  int sub = lane & 15, g = lane >> 4;                                            \
  float4 a0 = {0,0,0,0}, a1 = {0,0,0,0}, a2 = {0,0,0,0}, a3 = {0,0,0,0}, a4 = {0,0,0,0}; \
  _Pragma("unroll 2")                                                            \
  for (int t = 0; t < d; t += 4) {                                               \
    int jj = lj[t + g];                                                          \
    float ww = lw[t + g];                                                        \
    const float* base = XSRC + (size_t)jj * FD + (sub << 2);                     \
    float4 v0 = *(const float4*)(base);                                          \
    float4 v1 = *(const float4*)(base + 64);                                     \
    float4 v2 = *(const float4*)(base + 128);                                    \
    float4 v3 = *(const float4*)(base + 192);                                    \
    float4 v4 = *(const float4*)(base + 256);                                    \
    a0.x = fmaf(ww, v0.x, a0.x); a0.y = fmaf(ww, v0.y, a0.y);                    \
    a0.z = fmaf(ww, v0.z, a0.z); a0.w = fmaf(ww, v0.w, a0.w);                    \
    a1.x = fmaf(ww, v1.x, a1.x); a1.y = fmaf(ww, v1.y, a1.y);                    \
    a1.z = fmaf(ww, v1.z, a1.z); a1.w = fmaf(ww, v1.w, a1.w);                    \
    a2.x = fmaf(ww, v2.x, a2.x); a2.y = fmaf(ww, v2.y, a2.y);                    \
    a2.z = fmaf(ww, v2.z, a2.z); a2.w = fmaf(ww, v2.w, a2.w);                    \
    a3.x = fmaf(ww, v3.x, a3.x); a3.y = fmaf(ww, v3.y, a3.y);                    \
    a3.z = fmaf(ww, v3.z, a3.z); a3.w = fmaf(ww, v3.w, a3.w);                    \
    a4.x = fmaf(ww, v4.x, a4.x); a4.y = fmaf(ww, v4.y, a4.y);                    \
    a4.z = fmaf(ww, v4.z, a4.z); a4.w = fmaf(ww, v4.w, a4.w);                    \
  }                                                                              \
  _Pragma("unroll")                                                              \
  for (int off = 16; off <= 32; off <<= 1) {                                     \
    a0.x += __shfl_xor(a0.x, off); a0.y += __shfl_xor(a0.y, off);                \
    a0.z += __shfl_xor(a0.z, off); a0.w += __shfl_xor(a0.w, off);                \
    a1.x += __shfl_xor(a1.x, off); a1.y += __shfl_xor(a1.y, off);                \
    a1.z += __shfl_xor(a1.z, off); a1.w += __shfl_xor(a1.w, off);                \
    a2.x += __shfl_xor(a2.x, off); a2.y += __shfl_xor(a2.y, off);                \
    a2.z += __shfl_xor(a2.z, off); a2.w += __shfl_xor(a2.w, off);                \
    a3.x += __shfl_xor(a3.x, off); a3.y += __shfl_xor(a3.y, off);                \
    a3.z += __shfl_xor(a3.z, off); a3.w += __shfl_xor(a3.w, off);                \
    a4.x += __shfl_xor(a4.x, off); a4.y += __shfl_xor(a4.y, off);                \
    a4.z += __shfl_xor(a4.z, off); a4.w += __shfl_xor(a4.w, off);                \
  }                                                                              \
  float4 osel = (g == 0) ? a0 : (g == 1) ? a1 : (g == 2) ? a2 : a3;

// Y[r,:] = sum_{j in N(r)} X[j,:]
__global__ __launch_bounds__(256) void spmm_k(const int* __restrict__ adj, const int* __restrict__ deg,
                                              const float* __restrict__ X, float* __restrict__ Y, int n) {
  __shared__ int ljs[4][CAP];
  __shared__ float lws[4][CAP];
  int wv = threadIdx.x >> 6, lane = threadIdx.x & 63;
  int w = blockIdx.x * 4 + wv;
  if (w >= n) return;
  int* lj = ljs[wv]; float* lw = lws[wv];
  int d = deg[w];
  const int* row = adj + (size_t)w * CAP;
  for (int t0 = 0; t0 < d; t0 += 64) {
    int tt = t0 + lane;
    lj[tt] = (tt < d) ? row[tt] : 0;
    lw[tt] = (tt < d) ? 1.0f : 0.0f;
  }
  GATHER_CORE(X)
  float* yr = Y + (size_t)w * FD;
  *(float4*)(yr + g * 64 + (sub << 2)) = osel;
  if (g == 0) *(float4*)(yr + 256 + (sub << 2)) = a4;
}

// gather-scaled spmm (fused pool-gather + A@Xn):
// Y[r,:] = sum_{j in N(r)} vals[j] * Xsrc[idxmap[j], :]
__global__ __launch_bounds__(256) void spmm_gs_k(const int* __restrict__ adj, const int* __restrict__ deg,
                                                 const int* __restrict__ idxmap, const float* __restrict__ vals,
                                                 const float* __restrict__ Xsrc, float* __restrict__ Y, int n) {
  __shared__ int ljs[4][CAP];
  __shared__ float lws[4][CAP];
  int wv = threadIdx.x >> 6, lane = threadIdx.x & 63;
  int w = blockIdx.x * 4 + wv;
  if (w >= n) return;
  int* lj = ljs[wv]; float* lw = lws[wv];
  int d = deg[w];
  const int* row = adj + (size_t)w * CAP;
  for (int t0 = 0; t0 < d; t0 += 64) {
    int tt = t0 + lane;
    int j = (tt < d) ? row[tt] : -1;
    lj[tt] = (j >= 0) ? idxmap[j] : 0;
    lw[tt] = (j >= 0) ? vals[j] : 0.0f;
  }
  GATHER_CORE(Xsrc)
  float* yr = Y + (size_t)w * FD;
  *(float4*)(yr + g * 64 + (sub << 2)) = osel;
  if (g == 0) *(float4*)(yr + 256 + (sub << 2)) = a4;
}

// fused unpool + A@Xn: source row = inv[col] into pooled X, skip if -1
__global__ __launch_bounds__(256) void mspmm_k(const int* __restrict__ adj, const int* __restrict__ deg,
                                               const int* __restrict__ inv,
                                               const float* __restrict__ Xp, float* __restrict__ Y, int n) {
  __shared__ int ljs[4][CAP];
  __shared__ float lws[4][CAP];
  int wv = threadIdx.x >> 6, lane = threadIdx.x & 63;
  int w = blockIdx.x * 4 + wv;
  if (w >= n) return;
  int* lj = ljs[wv]; float* lw = lws[wv];
  int d = deg[w];
  const int* row = adj + (size_t)w * CAP;
  for (int t0 = 0; t0 < d; t0 += 64) {
    int tt = t0 + lane;
    int p = -1;
    if (tt < d) p = inv[row[tt]];
    lj[tt] = p >= 0 ? p : 0;
    lw[tt] = p >= 0 ? 1.0f : 0.0f;
  }
  GATHER_CORE(Xp)
  float* yr = Y + (size_t)w * FD;
  *(float4*)(yr + g * 64 + (sub << 2)) = osel;
  if (g == 0) *(float4*)(yr + 256 + (sub << 2)) = a4;
}

// fused masked-softmax GAT row: out = elu( softmax_edges(LR(es_i+ed_j)) @ h )
__global__ __launch_bounds__(256) void gat_k(const int* __restrict__ adj, const int* __restrict__ deg,
                                             const float* __restrict__ h, const float* __restrict__ es,
                                             const float* __restrict__ ed, float* __restrict__ out, int n) {
  __shared__ int ljs[4][CAP];
  __shared__ float lws[4][CAP];
  int wv = threadIdx.x >> 6, lane = threadIdx.x & 63;
  int w = blockIdx.x * 4 + wv;
  if (w >= n) return;
  int* lj = ljs[wv]; float* lw = lws[wv];
  int d = deg[w];
  const int* row = adj + (size_t)w * CAP;
  float esr = es[w];
  float m = -INFINITY;
  for (int t0 = 0; t0 < d; t0 += 64) {
    int tt = t0 + lane;
    int j = (tt < d) ? row[tt] : 0;
    float e = -INFINITY;
    if (tt < d) {
      e = esr + ed[j];
      e = e >= 0.f ? e : 0.2f * e;
    }
    lj[tt] = j;
    lw[tt] = e;
    m = fmaxf(m, e);
  }
  #pragma unroll
  for (int off = 32; off; off >>= 1) m = fmaxf(m, __shfl_xor(m, off));
  float zacc = 0.f;
  for (int t0 = 0; t0 < d; t0 += 64) {
    int tt = t0 + lane;
    float wgt = expf(lw[tt] - m);
    lw[tt] = wgt;
    zacc += wgt;
  }
  #pragma unroll
  for (int off = 32; off; off >>= 1) zacc += __shfl_xor(zacc, off);
  GATHER_CORE(h)
  float* yr = out + (size_t)w * FD;
  float4 o;
  o.x = osel.x / zacc; o.y = osel.y / zacc; o.z = osel.z / zacc; o.w = osel.w / zacc;
  o.x = o.x > 0.f ? o.x : expm1f(o.x);
  o.y = o.y > 0.f ? o.y : expm1f(o.y);
  o.z = o.z > 0.f ? o.z : expm1f(o.z);
  o.w = o.w > 0.f ? o.w : expm1f(o.w);
  *(float4*)(yr + g * 64 + (sub << 2)) = o;
  if (g == 0) {
    float4 o4;
    o4.x = a4.x / zacc; o4.y = a4.y / zacc; o4.z = a4.z / zacc; o4.w = a4.w / zacc;
    o4.x = o4.x > 0.f ? o4.x : expm1f(o4.x);
    o4.y = o4.y > 0.f ? o4.y : expm1f(o4.y);
    o4.z = o4.z > 0.f ? o4.z : expm1f(o4.z);
    o4.w = o4.w > 0.f ? o4.w : expm1f(o4.w);
    *(float4*)(yr + 256 + (sub << 2)) = o4;
  }
}

// ---------------- fp32 tiled GEMM: C[n x 320] = A[n x K] @ W[K x 320] (+bias)(+add) ----------------
// 64x64 tile (480 blocks at n=6144 -> ~2 blocks/CU). Optional second A source
// (column-concat fusion): k >= ksplit reads A2 (both row-stride = their own K part).
__global__ __launch_bounds__(256) void gemm_k(const float* __restrict__ A, const float* __restrict__ A2,
                                              int ksplit,
                                              const float* __restrict__ W,
                                              const float* __restrict__ bias, const float* __restrict__ add,
                                              float* __restrict__ C, int n, int K) {
  __shared__ float As[16][68];
  __shared__ float Bs[16][68];
  int t = threadIdx.x;
  int tx = t & 15, ty = t >> 4;
  int row0 = blockIdx.x * 64, col0 = blockIdx.y * 64;
  float acc[4][4] = {};
  int ar = t >> 2;
  int ak = (t & 3) << 2;
  int bk = t >> 4;
  int bc = (t & 15) << 2;
  for (int k0 = 0; k0 < K; k0 += 16) {
    float4 av = make_float4(0.f, 0.f, 0.f, 0.f);
    int grow = row0 + ar;
    int kk = k0 + ak;
    if (grow < n) {
      const float* src;
      if (A2 && kk >= ksplit) src = A2 + (size_t)grow * (K - ksplit) + (kk - ksplit);
      else                    src = A  + (size_t)grow * (A2 ? ksplit : K) + kk;
      av = *(const float4*)src;
    }
    As[ak + 0][ar] = av.x; As[ak + 1][ar] = av.y; As[ak + 2][ar] = av.z; As[ak + 3][ar] = av.w;
    float4 bv = *(const float4*)(W + (size_t)(k0 + bk) * FD + col0 + bc);
    *(float4*)&Bs[bk][bc] = bv;
    __syncthreads();
#pragma unroll
    for (int kkk = 0; kkk < 16; ++kkk) {
      float af[4], bf[4];
      *(float4*)af = *(const float4*)&As[kkk][ty << 2];
      *(float4*)bf = *(const float4*)&Bs[kkk][tx << 2];
#pragma unroll
      for (int i = 0; i < 4; ++i)
#pragma unroll
        for (int j = 0; j < 4; ++j) acc[i][j] = fmaf(af[i], bf[j], acc[i][j]);
    }
    __syncthreads();
  }
#pragma unroll
  for (int i = 0; i < 4; ++i) {
    int r = row0 + (ty << 2) + i;
    if (r >= n) continue;
    int c = col0 + (tx << 2);
    float4 v;
    v.x = acc[i][0]; v.y = acc[i][1]; v.z = acc[i][2]; v.w = acc[i][3];
    if (bias) { v.x += bias[c]; v.y += bias[c + 1]; v.z += bias[c + 2]; v.w += bias[c + 3]; }
    if (add) {
      const float* ad = add + (size_t)r * FD + c;
      v.x += ad[0]; v.y += ad[1]; v.z += ad[2]; v.w += ad[3];
    }
    *(float4*)(C + (size_t)r * FD + c) = v;
  }
}

static inline unsigned cdiv(int a, int b) { return (unsigned)((a + b - 1) / b); }

static void launch_gemm(const float* A, const float* W, const float* bias, const float* add,
                        float* C, int n, int K, hipStream_t stream, const float* A2 = nullptr,
                        int ksplit = 0) {
  gemm_k<<<dim3(cdiv(n, 64), 5), dim3(256), 0, stream>>>(A, A2, ksplit, W, bias, add, C, n, K);
}

// ---------------- GAT helpers ----------------
__global__ __launch_bounds__(256) void esed_k(const float* __restrict__ h, const float* __restrict__ a,
                                              float* __restrict__ es, float* __restrict__ ed, int n) {
  int w = blockIdx.x * 4 + (threadIdx.x >> 6);
  int lane = threadIdx.x & 63;
  if (w >= n) return;
  const float* hr = h + (size_t)w * FD;
  const float* a2 = a + FD;
  float sa = 0.f, sb = 0.f;
#pragma unroll
  for (int c = 0; c < 5; ++c) {
    float hv = hr[lane + 64 * c];
    sa += hv * a[lane + 64 * c];
    sb += hv * a2[lane + 64 * c];
  }
  for (int o = 32; o; o >>= 1) { sa += __shfl_xor(sa, o); sb += __shfl_xor(sb, o); }
  if (lane == 0) { es[w] = sa; ed[w] = sb; }
}

// ---------------- pooling: fused score + key build + rank zero ----------------
// key = (score_bits << 32) | ~i  — distinct by construction; rank-by-count of
// greater keys reproduces jax.lax.top_k order exactly.
__global__ __launch_bounds__(256) void scorekey_k(const float* __restrict__ X, const float* __restrict__ pw,
                                                  const float* __restrict__ pb,
                                                  unsigned long long* __restrict__ keys,
                                                  int* __restrict__ rank, int n) {
  int w = blockIdx.x * 4 + (threadIdx.x >> 6);
  int lane = threadIdx.x & 63;
  if (w >= n) return;
  const float* xr = X + (size_t)w * FD;
  float s = 0.f;
#pragma unroll
  for (int c = 0; c < 5; ++c) s += xr[lane + 64 * c] * pw[lane + 64 * c];
  for (int o = 32; o; o >>= 1) s += __shfl_xor(s, o);
  if (lane == 0) {
    float u = (s + pb[0]) / 100.0f;
    float sc = 1.0f / (1.0f + expf(-u));
    keys[w] = ((unsigned long long)__float_as_uint(sc) << 32) | (unsigned int)(~w);
    rank[w] = 0;
  }
}

#define RANK_TILE 1024
__global__ __launch_bounds__(256) void rank_count_k(const unsigned long long* __restrict__ keys,
                                                    int n, int jchunk, int* __restrict__ rank) {
  __shared__ unsigned long long tile[RANK_TILE];
  int i = blockIdx.x * 256 + threadIdx.x;
  unsigned long long my = (i < n) ? keys[i] : 0ull;
  int j0 = blockIdx.y * jchunk;
  int jend = j0 + jchunk; if (jend > n) jend = n;
  int cnt = 0;
  for (int t0 = j0; t0 < jend; t0 += RANK_TILE) {
    int m = jend - t0; if (m > RANK_TILE) m = RANK_TILE;
    for (int t = threadIdx.x; t < m; t += 256) tile[t] = keys[t0 + t];
    __syncthreads();
    for (int t = 0; t < m; ++t) cnt += (tile[t] > my) ? 1 : 0;
    __syncthreads();
  }
  if (i < n && cnt) atomicAdd(&rank[i], cnt);
}

// writes idx (topk order), vals (score), and inv (new index or -1) in one pass
__global__ __launch_bounds__(256) void rank_scatter_k(const unsigned long long* __restrict__ keys,
                                                      const int* __restrict__ rank, int n, int k,
                                                      int* __restrict__ idx_out, float* __restrict__ vals_out,
                                                      int* __restrict__ inv) {
  int i = blockIdx.x * 256 + threadIdx.x;
  if (i >= n) return;
  int r = rank[i];
  inv[i] = (r < k) ? r : -1;
  if (r < k) {
    idx_out[r] = i;
    vals_out[r] = __uint_as_float((unsigned int)(keys[i] >> 32));
  }
}

__global__ void gather_scale_k(const float* __restrict__ X, const int* __restrict__ idx,
                               const float* __restrict__ vals, float* __restrict__ out, int k) {
  int i = blockIdx.x * 256 + threadIdx.x;
  if (i >= k * FD) return;
  int r = i / FD, c = i - r * FD;
  out[i] = X[(size_t)idx[r] * FD + c] * vals[r];
}

// ---------------- host ----------------
static inline dim3 wgrid(int n) { return dim3((unsigned)((n + 3) / 4)); }

struct TopkBufs { unsigned long long* keys; int* rank; };

static void launch_topk(int n, int k, int* idx_out, float* vals_out, int* inv,
                        TopkBufs tb, hipStream_t stream) {
  const int JS = 8;
  int jchunk = (n + JS - 1) / JS;
  rank_count_k<<<dim3(cdiv(n, 256), JS), dim3(256), 0, stream>>>(tb.keys, n, jchunk, tb.rank);
  rank_scatter_k<<<cdiv(n, 256), dim3(256), 0, stream>>>(tb.keys, tb.rank, n, k, idx_out, vals_out, inv);
}

extern "C" void kernel_launch(void* const* d_in, const int* in_sizes, int n_in,
                              void* d_out, int out_size, void* d_ws, size_t ws_size,
                              hipStream_t stream) {
  const float* A      = (const float*)d_in[0];
  const float* X0     = (const float*)d_in[1];
  const float* sg_W   = (const float*)d_in[2];
  const float* sg_a   = (const float*)d_in[3];
  const float* bg_W   = (const float*)d_in[4];
  const float* bg_a   = (const float*)d_in[5];
  const float* eg_W   = (const float*)d_in[6];
  const float* eg_a   = (const float*)d_in[7];
  const float* down_W = (const float*)d_in[8];
  const float* down_b = (const float*)d_in[9];
  const float* up_W   = (const float*)d_in[10];
  const float* up_b   = (const float*)d_in[11];
  const float* pool_w = (const float*)d_in[12];
  const float* pool_b = (const float*)d_in[13];
  float* out = (float*)d_out;
  char* ws = (char*)d_ws;

  size_t off = 0;
  auto alloc = [&](size_t bytes) -> char* {
    char* p = ws + off;
    off += (bytes + 255) & ~(size_t)255;
    return p;
  };
  int* adj0  = (int*)alloc((size_t)N0 * CAP * 4);
  int* deg0  = (int*)alloc((size_t)N0 * 4);
  int* adj1a = (int*)alloc((size_t)NN1 * CAP * 4);
  int* deg1a = (int*)alloc((size_t)NN1 * 4);
  int* adj1b = (int*)alloc((size_t)NN1 * CAP * 4);
  int* deg1b = (int*)alloc((size_t)NN1 * 4);
  int* adj2  = (int*)alloc((size_t)NN2 * CAP * 4);
  int* deg2  = (int*)alloc((size_t)NN2 * 4);
  int* inv0a = (int*)alloc((size_t)N0 * 4);
  int* inv0b = (int*)alloc((size_t)N0 * 4);
  int* inv1a = (int*)alloc((size_t)NN1 * 4);
  int* inv1b = (int*)alloc((size_t)NN1 * 4);
  int* idx0a = (int*)alloc((size_t)NN1 * 4);
  int* idx0b = (int*)alloc((size_t)NN1 * 4);
  int* idx1a = (int*)alloc((size_t)NN2 * 4);
  int* idx1b = (int*)alloc((size_t)NN2 * 4);
  unsigned long long* keys = (unsigned long long*)alloc((size_t)N0 * 8);
  int* rankb = (int*)alloc((size_t)N0 * 4);
  float* vals   = (float*)alloc((size_t)N0 * 4);
  float* es     = (float*)alloc((size_t)N0 * 4);
  float* ed     = (float*)alloc((size_t)N0 * 4);
  float* hbuf   = (float*)alloc((size_t)N0 * FD * 4);
  float* S      = (float*)alloc((size_t)N0 * FD * 4);
  float* Xcur   = (float*)alloc((size_t)N0 * FD * 4);
  float* d0a    = (float*)alloc((size_t)N0 * FD * 4);
  float* d1a    = (float*)alloc((size_t)NN1 * FD * 4);
  float* d0b    = (float*)alloc((size_t)N0 * FD * 4);
  float* d1b    = (float*)alloc((size_t)NN1 * FD * 4);
  float* Xp2    = (float*)alloc((size_t)NN2 * FD * 4);
  float* Xb     = (float*)alloc((size_t)NN2 * FD * 4);
  float* Xu1    = (float*)alloc((size_t)NN1 * FD * 4);
  float* Xu0    = (float*)alloc((size_t)N0 * FD * 4);

  TopkBufs tb{keys, rankb};
  dim3 b256(256);

  build_adj_k<<<wgrid(N0), b256, 0, stream>>>(A, adj0, deg0);

  float* orgX = out + (size_t)N0 * FD;   // "start" output, also org_X
  launch_gemm(X0, sg_W, nullptr, nullptr, hbuf, N0, FD, stream);
  esed_k<<<wgrid(N0), b256, 0, stream>>>(hbuf, sg_a, es, ed, N0);
  gat_k<<<wgrid(N0), b256, 0, stream>>>(adj0, deg0, hbuf, es, ed, orgX, N0);

  const float* Xin = orgX;
  for (int pass = 0; pass < 2; ++pass) {
    int* idx0p = pass ? idx0b : idx0a;
    int* inv0p = pass ? inv0b : inv0a;
    int* idx1p = pass ? idx1b : idx1a;
    int* inv1p = pass ? inv1b : inv1a;
    int* adj1p = pass ? adj1b : adj1a;
    int* deg1p = pass ? deg1b : deg1a;
    float* d0p = pass ? d0b : d0a;
    float* d1p = pass ? d1b : d1a;

    // ---- down level 0 (n = N0) ----
    spmm_k<<<wgrid(N0), b256, 0, stream>>>(adj0, deg0, Xin, S, N0);
    launch_gemm(S, down_W, down_b, nullptr, d0p, N0, FD, stream);
    scorekey_k<<<wgrid(N0), b256, 0, stream>>>(d0p, pool_w, pool_b, keys, rankb, N0);
    launch_topk(N0, NN1, idx0p, vals, inv0p, tb, stream);
    sub_adj_k<<<wgrid(NN1), b256, 0, stream>>>(adj0, deg0, idx0p, inv0p, adj1p, deg1p, NN1);

    // ---- down level 1 (n = NN1): pool-gather fused into the spmm ----
    spmm_gs_k<<<wgrid(NN1), b256, 0, stream>>>(adj1p, deg1p, idx0p, vals, d0p, S, NN1);
    launch_gemm(S, down_W + FD * FD, down_b + FD, nullptr, d1p, NN1, FD, stream);
    scorekey_k<<<wgrid(NN1), b256, 0, stream>>>(d1p, pool_w + FD, pool_b + 1, keys, rankb, NN1);
    launch_topk(NN1, NN2, idx1p, vals, inv1p, tb, stream);
    gather_scale_k<<<cdiv(NN2 * FD, 256), b256, 0, stream>>>(d1p, idx1p, vals, Xp2, NN2);
    sub_adj_k<<<wgrid(NN2), b256, 0, stream>>>(adj1p, deg1p, idx1p, inv1p, adj2, deg2, NN2);

    // ---- bottom GAT (n = NN2) ----
    launch_gemm(Xp2, bg_W, nullptr, nullptr, hbuf, NN2, FD, stream);
    esed_k<<<wgrid(NN2), b256, 0, stream>>>(hbuf, bg_a, es, ed, NN2);
    gat_k<<<wgrid(NN2), b256, 0, stream>>>(adj2, deg2, hbuf, es, ed, Xb, NN2);

    // ---- up path: ALWAYS pass-1 ("a") graph state, per reference indexing ----
    mspmm_k<<<wgrid(NN1), b256, 0, stream>>>(adj1a, deg1a, inv1a, Xb, S, NN1);
    launch_gemm(S, up_W, up_b, d1a, Xu1, NN1, FD, stream);
    mspmm_k<<<wgrid(N0), b256, 0, stream>>>(adj0, deg0, inv0a, Xu1, S, N0);
    launch_gemm(S, up_W + FD * FD, up_b + FD, d0a, Xu0, N0, FD, stream);

    // ---- end GAT on concat([Xu0, org_X]) fused into the GEMM A-loader ----
    launch_gemm(Xu0, eg_W, nullptr, nullptr, hbuf, N0, 2 * FD, stream, orgX, FD);
    esed_k<<<wgrid(N0), b256, 0, stream>>>(hbuf, eg_a, es, ed, N0);
    float* egout = pass ? out : Xcur;
    gat_k<<<wgrid(N0), b256, 0, stream>>>(adj0, deg0, hbuf, es, ed, egout, N0);
    Xin = egout;
  }
}